// Round 1
// baseline (339.517 us; speedup 1.0000x reference)
//
#include <hip/hip_runtime.h>

typedef __attribute__((ext_vector_type(4))) float f32x4;
typedef __attribute__((ext_vector_type(4))) unsigned int u32x4;
typedef __attribute__((ext_vector_type(8))) unsigned short u16x8;
typedef __attribute__((ext_vector_type(8))) __bf16 bf16x8;

#define DEVFN static __device__ __forceinline__

DEVFN unsigned short f2b(float f) {
  unsigned u = __builtin_bit_cast(unsigned, f);
  u += 0x7fffu + ((u >> 16) & 1u);
  return (unsigned short)(u >> 16);
}
DEVFN float b2f(unsigned short h) {
  unsigned u = ((unsigned)h) << 16;
  return __builtin_bit_cast(float, u);
}
DEVFN float sigf(float x) { return 1.0f / (1.0f + __expf(-x)); }

// ---------------- workspace layout (bytes) ----------------
#define XP_BYTES (16ull*66*66*288*2)        // padded bf16 NHWC input (zero borders + ch pad)
#define WT_BYTES (9ull*512*288*2)           // conv weights: [tap][o][ci] bf16
#define W2_BYTES (64ull*512*2)              // head weights: [o(64)][k(512)] bf16
#define CV_BYTES (65536ull*512*2)           // conv output, [pixel][512] bf16
#define PS_BYTES (256ull*512*2*4)           // BN partial sums
#define XP_OFF 0ull
#define WT_OFF (XP_OFF + XP_BYTES)
#define W2_OFF (WT_OFF + WT_BYTES)
#define CV_OFF (W2_OFF + W2_BYTES)
#define PS_OFF (CV_OFF + CV_BYTES)
#define SB_OFF (PS_OFF + PS_BYTES)

#define GLOAD16(gp, lp) __builtin_amdgcn_global_load_lds( \
    (__attribute__((address_space(1))) void*)(gp),        \
    (__attribute__((address_space(3))) void*)(lp), 16, 0, 0)

// ---------------- prep kernels ----------------
__global__ void k_zero(unsigned char* p, unsigned long long n16) {
  unsigned long long i = (unsigned long long)blockIdx.x * 256u + threadIdx.x;
  if (i < n16) ((u32x4*)p)[i] = (u32x4){0u, 0u, 0u, 0u};
}

// input1 (16,256,64,64) f32 -> Xp[b][y+1][x+1][c] bf16 (c<256)
__global__ void k_pack_in(const float* __restrict__ in1, unsigned short* __restrict__ xp) {
  __shared__ float lt[32][65];
  int tid = threadIdx.x;
  int bid = blockIdx.x;
  int cg = bid & 7, y = (bid >> 3) & 63, b = bid >> 9;
  int x = tid & 63, cr = tid >> 6;
#pragma unroll
  for (int i = 0; i < 8; ++i) {
    int cl = i * 4 + cr;
    lt[cl][x] = in1[(((size_t)(b * 256 + cg * 32 + cl) * 64 + y) * 64) + x];
  }
  __syncthreads();
  int xx = tid >> 2, ch = tid & 3;
  u16x8 v;
#pragma unroll
  for (int j = 0; j < 8; ++j) v[j] = f2b(lt[ch * 8 + j][xx]);
  size_t base = ((size_t)((b * 66 + y + 1) * 66 + xx + 1)) * 288 + cg * 32 + ch * 8;
  *(u16x8*)(xp + base) = v;
}

// grid channels: c=256 -> x, c=257 -> y
__global__ void k_pack_grid(unsigned short* __restrict__ xp) {
  int pid = blockIdx.x * 256 + threadIdx.x;
  int b = pid >> 12, pi = pid & 4095, y = pi >> 6, x = pi & 63;
  unsigned v = (unsigned)f2b((float)x) | ((unsigned)f2b((float)y) << 16);
  *(unsigned*)(xp + ((size_t)((b * 66 + y + 1) * 66 + x + 1)) * 288 + 256) = v;
}

// w_conv (512,258,3,3) -> Wt[tap][o][ci] bf16, ci padded to 288
__global__ void k_pack_w(const float* __restrict__ wc, unsigned short* __restrict__ wt) {
  int tap = blockIdx.x >> 9, o = blockIdx.x & 511, ci = threadIdx.x;  // 288 threads
  float v = (ci < 258) ? wc[(size_t)(o * 258 + ci) * 9 + tap] : 0.f;
  wt[((size_t)(tap * 512 + o)) * 288 + ci] = f2b(v);
}

// head weights: o<10 w_loc, 10..57 w_mask, pad to 64
__global__ void k_pack_w2(const float* __restrict__ wl, const float* __restrict__ wm,
                          unsigned short* __restrict__ w2) {
  int idx = blockIdx.x * 256 + threadIdx.x;  // 32768
  int o = idx >> 9, k = idx & 511;
  float v = 0.f;
  if (o < 10) v = wl[o * 512 + k];
  else if (o < 58) v = wm[(o - 10) * 512 + k];
  w2[idx] = f2b(v);
}

// ---------------- conv: implicit GEMM 128x128 tile, BK=64 (2 K-halves) ----------------
__global__ __launch_bounds__(256) void k_conv(const unsigned short* __restrict__ xp,
                                              const unsigned short* __restrict__ wt,
                                              unsigned short* __restrict__ cv) {
  __shared__ unsigned short lds[16384];  // A bytes [0,16384), B bytes [16384,32768); epilogue reuses as 128x128
  int tid = threadIdx.x;
  int lane = tid & 63, wv = tid >> 6;
  int bid = blockIdx.x;
  int nt = bid & 3, mt = bid >> 2;
  int n0 = nt * 128;
  int pix0 = mt * 128;
  int b = pix0 >> 12;
  int pi0 = pix0 & 4095;

  // staging: chunk q = tid + 256*i, 16B each. slot unit u'=tid&7, row p = tid>>3 + 32*i.
  // XOR swizzle: slot (r,u') holds global k-unit u'^(r&7). p&7 is i-invariant.
  int u_slot = tid & 7;
  int rowsub = (tid >> 3) & 7;
  int g8 = u_slot ^ rowsub;   // global 16B-unit (0..7) this thread fetches
  int gk = g8 & 3;            // unit within K-half
  int ghalf = g8 >> 2;        // which K-half of the stage

  size_t aBase[4], bBase[4];
#pragma unroll
  for (int i = 0; i < 4; ++i) {
    int p = (tid >> 3) + 32 * i;
    int pi = pi0 + p;
    int yy = pi >> 6, xx = pi & 63;
    aBase[i] = ((size_t)((b * 66 + yy) * 66 + xx)) * 576;  // 288 ch * 2B
    bBase[i] = ((size_t)(n0 + p)) * 576;
  }

  f32x4 acc[4][4];
#pragma unroll
  for (int mf = 0; mf < 4; ++mf)
#pragma unroll
    for (int nf = 0; nf < 4; ++nf) acc[mf][nf] = (f32x4){0.f, 0.f, 0.f, 0.f};

  int wm = wv >> 1, wn = wv & 1;
  int arow[4], brow[4];
#pragma unroll
  for (int f = 0; f < 4; ++f) {
    arow[f] = wm * 64 + f * 16 + (lane & 15);
    brow[f] = wn * 64 + f * 16 + (lane & 15);
  }
  int ko = lane >> 4;
  int xm = lane & 7;  // frag-read swizzle mask (= row&7 for all frag rows)

  auto comp = [&](int kk) {
    bf16x8 af[4], bg[4];
#pragma unroll
    for (int f = 0; f < 4; ++f) {
      int unit = (kk * 4 + ko) ^ xm;
      af[f] = *(const bf16x8*)(lds + arow[f] * 64 + unit * 8);
      bg[f] = *(const bf16x8*)(lds + 8192 + brow[f] * 64 + unit * 8);
    }
#pragma unroll
    for (int mf = 0; mf < 4; ++mf)
#pragma unroll
      for (int nf = 0; nf < 4; ++nf)
        acc[mf][nf] = __builtin_amdgcn_mfma_f32_16x16x32_bf16(af[mf], bg[nf], acc[mf][nf], 0, 0, 0);
  };

#pragma unroll 1
  for (int s = 0; s < 41; ++s) {  // 81 K-halves of 32 (9 taps x 9 ci-blocks), 2 per stage
    int hh = 2 * s + ghalf;
    if (hh > 80) hh = 80;                 // dup-load, region unused on last stage
    int tap = (hh * 57) >> 9;             // hh/9
    int ci0 = (hh - tap * 9) * 32;
    int dy = (tap * 11) >> 5;             // tap/3
    int dx = tap - dy * 3;
    size_t aoff = ((size_t)((dy * 66 + dx) * 288 + ci0 + gk * 8)) * 2;
    size_t boff = ((size_t)(tap * 512 * 288 + ci0 + gk * 8)) * 2;
#pragma unroll
    for (int i = 0; i < 4; ++i) {
      GLOAD16(((const unsigned char*)xp) + aBase[i] + aoff,
              ((unsigned char*)lds) + (tid + 256 * i) * 16);
      GLOAD16(((const unsigned char*)wt) + bBase[i] + boff,
              ((unsigned char*)lds) + 16384 + (tid + 256 * i) * 16);
    }
    __syncthreads();
    comp(0);
    if (s < 40) comp(1);
    __syncthreads();
  }

  // epilogue: acc -> bf16 via LDS repack -> coalesced 16B stores
#pragma unroll
  for (int mf = 0; mf < 4; ++mf)
#pragma unroll
    for (int nf = 0; nf < 4; ++nf)
#pragma unroll
      for (int r = 0; r < 4; ++r) {
        int row = wm * 64 + mf * 16 + (lane >> 4) * 4 + r;
        int col = wn * 64 + nf * 16 + (lane & 15);
        lds[row * 128 + col] = f2b(acc[mf][nf][r]);
      }
  __syncthreads();
#pragma unroll
  for (int i = 0; i < 8; ++i) {
    int q = tid + 256 * i;  // 2048 chunks of 16B
    int prow = q >> 4, c16 = q & 15;
    *(u16x8*)(cv + ((size_t)(pix0 + prow) * 512 + n0 + c16 * 8)) = *(const u16x8*)(lds + q * 8);
  }
}

// ---------------- BN stats (deterministic 2-stage) ----------------
__global__ void k_stats(const unsigned short* __restrict__ cv, float* __restrict__ ps) {
  int tid = threadIdx.x, bb = blockIdx.x;  // 256 blocks, 256 pixels each
  const unsigned* cp = (const unsigned*)cv;
  float s0 = 0, s1 = 0, q0 = 0, q1 = 0;
#pragma unroll 4
  for (int it = 0; it < 256; ++it) {
    unsigned v = cp[((size_t)(bb * 256 + it)) * 256 + tid];
    float f0 = b2f((unsigned short)(v & 0xffff));
    float f1 = b2f((unsigned short)(v >> 16));
    s0 += f0; q0 += f0 * f0; s1 += f1; q1 += f1 * f1;
  }
  f32x4 o = {s0, q0, s1, q1};
  *(f32x4*)(ps + (size_t)bb * 1024 + tid * 4) = o;
}

__global__ void k_bnfinal(const float* __restrict__ ps, const float* __restrict__ gamma,
                          const float* __restrict__ beta, float* __restrict__ sb) {
  int c = threadIdx.x;  // 512
  float s = 0, q = 0;
  for (int bb = 0; bb < 256; ++bb) {
    s += ps[(size_t)bb * 1024 + (c >> 1) * 4 + (c & 1) * 2];
    q += ps[(size_t)bb * 1024 + (c >> 1) * 4 + (c & 1) * 2 + 1];
  }
  float mean = s * (1.0f / 65536.0f);
  float var = q * (1.0f / 65536.0f) - mean * mean;
  float sc = gamma[c] / sqrtf(var + 1e-5f);
  sb[c * 2] = sc;
  sb[c * 2 + 1] = beta[c] - mean * sc;
}

__global__ void k_bnleaky(unsigned short* __restrict__ cv, const float* __restrict__ sb) {
  size_t i = (size_t)blockIdx.x * 256 + threadIdx.x;  // 4,194,304 chunks of 8
  int cb = ((int)i & 63) * 8;
  u16x8 v = *(u16x8*)(cv + i * 8);
#pragma unroll
  for (int j = 0; j < 8; ++j) {
    int c = cb + j;
    float f = b2f(v[j]) * sb[c * 2] + sb[c * 2 + 1];
    f = (f > 0.f) ? f : 0.1f * f;
    v[j] = f2b(f);
  }
  *(u16x8*)(cv + i * 8) = v;
}

// ---------------- head: 256px x 64out GEMM (K=512) + full decode ----------------
__global__ __launch_bounds__(256) void k_head(const unsigned short* __restrict__ cv,
                                              const unsigned short* __restrict__ w2,
                                              const float* __restrict__ bl,
                                              const float* __restrict__ bm,
                                              float* __restrict__ out) {
  __shared__ float lo[256][59];
  int tid = threadIdx.x, lane = tid & 63, wv = tid >> 6;
  int pix0 = blockIdx.x * 256;
  f32x4 acc[4][4];
#pragma unroll
  for (int mf = 0; mf < 4; ++mf)
#pragma unroll
    for (int nf = 0; nf < 4; ++nf) acc[mf][nf] = (f32x4){0.f, 0.f, 0.f, 0.f};
  int ko = lane >> 4;

  for (int k0 = 0; k0 < 512; k0 += 32) {
    bf16x8 a[4], bg[4];
#pragma unroll
    for (int f = 0; f < 4; ++f) {
      bg[f] = *(const bf16x8*)(w2 + (size_t)(f * 16 + (lane & 15)) * 512 + k0 + ko * 8);
      a[f] = *(const bf16x8*)(cv + (size_t)(pix0 + wv * 64 + f * 16 + (lane & 15)) * 512 + k0 + ko * 8);
    }
#pragma unroll
    for (int mf = 0; mf < 4; ++mf)
#pragma unroll
      for (int nf = 0; nf < 4; ++nf)
        acc[mf][nf] = __builtin_amdgcn_mfma_f32_16x16x32_bf16(a[mf], bg[nf], acc[mf][nf], 0, 0, 0);
  }

  float bias[4]; int colv[4];
#pragma unroll
  for (int nf = 0; nf < 4; ++nf) {
    int col = nf * 16 + (lane & 15);
    colv[nf] = col;
    bias[nf] = (col < 10) ? bl[col] : ((col < 58) ? bm[col - 10] : 0.f);
  }
#pragma unroll
  for (int mf = 0; mf < 4; ++mf)
#pragma unroll
    for (int nf = 0; nf < 4; ++nf)
#pragma unroll
      for (int r = 0; r < 4; ++r) {
        int row = wv * 64 + mf * 16 + (lane >> 4) * 4 + r;
        if (colv[nf] < 58) lo[row][colv[nf]] = acc[mf][nf][r] + bias[nf];
      }
  __syncthreads();

  // ---- decode: one thread = one pixel ----
  int pix = pix0 + tid;
  int b = pix >> 12, pi = pix & 4095;
  int yi = pi >> 6, xi = pi & 63;
  float X = (float)xi, Y = (float)yi;
  const float* O = lo[tid];

  float* outP = out;
  float* outB = out + 655360;
  float* outOL = out + 1572864;
  float* outOC = out + 2752512;
  float* outML = out + 3932160;
  float* outMC = out + 4521984;
  float* outWC = out + 5111808;
  float* outOD = out + 5636096;

  float pr[10];
#pragma unroll
  for (int i = 0; i < 10; ++i) { pr[i] = O[i]; outP[(size_t)pix * 10 + i] = pr[i]; }
  const float st = 8.f, ist = 0.125f;
  float l0 = pr[0] * pr[0] * st, l1 = pr[1] * pr[1] * st;
  float l2 = pr[2] * pr[2] * st, l3 = pr[3] * pr[3] * st;
  float cx = X * st + 4.f, cy = Y * st + 4.f;
  float xmin = cx - l3, ymin = cy - l0, xmax = cx + l1, ymax = cy + l2;
  float w = l1 + l3, h = l0 + l2;
  float xc = 0.5f * (xmax + xmin), yc = 0.5f * (ymax + ymin);
  float r = sigf(pr[8]);
  float maskr = (r > 0.9f) ? 0.f : 1.f;
  float s0 = sigf(pr[4]) * maskr, s1 = sigf(pr[5]) * maskr;
  float s2 = sigf(pr[6]) * maskr, s3 = sigf(pr[7]) * maskr;
  float conf = sigf(pr[9]);
  {
    size_t bo = (size_t)pix * 14;
    outB[bo + 0] = xc; outB[bo + 1] = yc; outB[bo + 2] = w; outB[bo + 3] = h;
    outB[bo + 4] = s0; outB[bo + 5] = s1; outB[bo + 6] = s2; outB[bo + 7] = s3;
    outB[bo + 8] = r;  outB[bo + 9] = l0; outB[bo + 10] = l1; outB[bo + 11] = l2;
    outB[bo + 12] = l3; outB[bo + 13] = conf;
  }
  float x1 = xmin + s0 * w, x7 = xmax - s2 * w;
  float y5 = ymin + s1 * h, y3 = ymax - s3 * h;
  float xob = 0.5f * (x1 + x7), yob = 0.5f * (y5 + y3);
  float ov[22];
#pragma unroll
  for (int j = 0; j < 22; ++j) ov[j] = sigf(O[28 + j]);
  float eps = ceilf(0.01f * w);
  bool c0 = x1 < xmin + eps;
  float xp0 = c0 ? x1 : xmin + ov[0] * (x1 - xmin);
  float yp0 = c0 ? ymin + ov[0] * (y3 - ymin)
                 : (y3 - ymin) / (xmin - x1 + 1e-8f) * (xp0 - x1) + ymin;
  bool c2 = x1 > xmax - eps;
  float xp2 = c2 ? x1 : xmax - ov[1] * (xmax - x1);
  float yp2 = c2 ? ymin + ov[1] * (y5 - ymin)
                 : (y5 - ymin) / (xmax - x1 + 1e-8f) * (xp2 - x1) + ymin;
  bool c6 = x7 < xmin + eps;
  float xp6 = c6 ? x7 : xmin + ov[2] * (x7 - xmin);
  float yp6 = c6 ? ymax - ov[2] * (ymax - y3)
                 : (y3 - ymax) / (xmin - x7 + 1e-8f) * (xp6 - x7) + ymax;
  bool c8c = x7 > xmax - eps;
  float xp8 = c8c ? x7 : xmax - ov[3] * (xmax - x7);
  float yp8 = c8c ? ymax - ov[3] * (ymax - y5)
                  : (y5 - ymax) / (xmax - x7 + 1e-8f) * (xp8 - x7) + ymax;

  size_t olb = ((size_t)b * 18) * 4096 + pi;
  outOL[olb + 0 * 4096] = yp0 * ist + 1.f - Y;
  outOL[olb + 1 * 4096] = xp0 * ist + 1.f - X;
  outOL[olb + 2 * 4096] = ymin * ist + 1.f - Y;
  outOL[olb + 3 * 4096] = x1 * ist - X;
  outOL[olb + 4 * 4096] = yp2 * ist + 1.f - Y;
  outOL[olb + 5 * 4096] = xp2 * ist - 1.f - X;
  outOL[olb + 6 * 4096] = y3 * ist - Y;
  outOL[olb + 7 * 4096] = xmin * ist + 1.f - X;
  outOL[olb + 8 * 4096] = 0.f;
  outOL[olb + 9 * 4096] = 0.f;
  outOL[olb + 10 * 4096] = y5 * ist - Y;
  outOL[olb + 11 * 4096] = xmax * ist - 1.f - X;
  outOL[olb + 12 * 4096] = yp6 * ist - 1.f - Y;
  outOL[olb + 13 * 4096] = xp6 * ist + 1.f - X;
  outOL[olb + 14 * 4096] = ymax * ist - 1.f - Y;
  outOL[olb + 15 * 4096] = x7 * ist - X;
  outOL[olb + 16 * 4096] = yp8 * ist - 1.f - Y;
  outOL[olb + 17 * 4096] = xp8 * ist - 1.f - X;

  float A1 = x1 - xmax, B1 = ymin - y5, A2 = xmin - x7, B2 = y3 - ymax;
  float width = 0.5f * (sqrtf(A1 * A1 + B1 * B1) + sqrtf(A2 * A2 + B2 * B2));
  float C1 = xmin - x1, D1 = y3 - ymin, C2 = x7 - xmax, D2 = ymax - y5;
  float height = 0.5f * (sqrtf(C1 * C1 + D1 * D1) + sqrtf(C2 * C2 + D2 * D2));
  float ang = 0.5f * (atanf((y5 - ymin) / (xmax - x1 + 1e-4f)) +
                      atanf((ymax - y3) / (x7 - xmin + 1e-4f)));
  float ca = cosf(ang), sa = sinf(ang);
  const float DD = 0.70710678118654752f;
  const float dyc[9] = {DD, 1.f, DD, 0.f, 0.f, 0.f, -DD, -1.f, -DD};
  const float dxc[9] = {DD, 0.f, -DD, 1.f, 0.f, -1.f, DD, 0.f, -DD};
  size_t ocb = ((size_t)b * 18) * 4096 + pi;
  size_t odb = (size_t)pix * 18;
#pragma unroll
  for (int k = 0; k < 9; ++k) {
    float xd = xob - 0.5f * width + ov[13 + k] * width;
    float yd = yob - 0.5f * height + ov[4 + k] * height;
    float ddx = xd - xob, ddy = yd - yob;
    float xd0 = ca * ddx - sa * ddy + xob;
    float xdc = fminf(fmaxf(xd0, xmin), xmax);
    float yd0 = sa * ddx + ca * ddy + yob;
    float ydc = fminf(fmaxf(yd0, ymin), ymax);
    outOC[ocb + (size_t)(2 * k) * 4096] = ydc * ist + dyc[k] - Y;
    outOC[ocb + (size_t)(2 * k + 1) * 4096] = xdc * ist + dxc[k] - X;
    outOD[odb + k] = xdc;
    outOD[odb + 9 + k] = ydc;
  }
  size_t mlb = ((size_t)b * 9) * 4096 + pi;
#pragma unroll
  for (int k = 0; k < 9; ++k) outML[mlb + (size_t)k * 4096] = sigf(O[10 + k]);
#pragma unroll
  for (int k = 0; k < 9; ++k) outMC[mlb + (size_t)k * 4096] = sigf(O[19 + k]);
  float v8[8], mx = -1e30f;
#pragma unroll
  for (int k = 0; k < 8; ++k) { v8[k] = O[50 + k]; mx = fmaxf(mx, v8[k]); }
  float sm = 0.f;
#pragma unroll
  for (int k = 0; k < 8; ++k) { v8[k] = __expf(v8[k] - mx); sm += v8[k]; }
  float inv = 1.f / sm;
  size_t wcb = ((size_t)b * 8) * 4096 + pi;
#pragma unroll
  for (int k = 0; k < 8; ++k) outWC[wcb + (size_t)k * 4096] = v8[k] * inv;
}

// ---------------- launch ----------------
extern "C" void kernel_launch(void* const* d_in, const int* in_sizes, int n_in,
                              void* d_out, int out_size, void* d_ws, size_t ws_size,
                              hipStream_t stream) {
  const float* in1 = (const float*)d_in[0];
  const float* wconv = (const float*)d_in[1];
  const float* gamma = (const float*)d_in[2];
  const float* beta = (const float*)d_in[3];
  const float* wloc = (const float*)d_in[4];
  const float* bloc = (const float*)d_in[5];
  const float* wmask = (const float*)d_in[6];
  const float* bmask = (const float*)d_in[7];
  unsigned char* ws = (unsigned char*)d_ws;
  unsigned short* xp = (unsigned short*)(ws + XP_OFF);
  unsigned short* wt = (unsigned short*)(ws + WT_OFF);
  unsigned short* w2 = (unsigned short*)(ws + W2_OFF);
  unsigned short* cv = (unsigned short*)(ws + CV_OFF);
  float* ps = (float*)(ws + PS_OFF);
  float* sb = (float*)(ws + SB_OFF);
  float* out = (float*)d_out;

  k_zero<<<dim3((unsigned)((XP_BYTES / 16 + 255) / 256)), dim3(256), 0, stream>>>(
      (unsigned char*)xp, XP_BYTES / 16);
  k_pack_in<<<dim3(8192), dim3(256), 0, stream>>>(in1, xp);
  k_pack_grid<<<dim3(256), dim3(256), 0, stream>>>(xp);
  k_pack_w<<<dim3(9 * 512), dim3(288), 0, stream>>>(wconv, wt);
  k_pack_w2<<<dim3(128), dim3(256), 0, stream>>>(wloc, wmask, w2);
  k_conv<<<dim3(2048), dim3(256), 0, stream>>>(xp, wt, cv);
  k_stats<<<dim3(256), dim3(256), 0, stream>>>(cv, ps);
  k_bnfinal<<<dim3(1), dim3(512), 0, stream>>>(ps, gamma, beta, sb);
  k_bnleaky<<<dim3(16384), dim3(256), 0, stream>>>(cv, sb);
  k_head<<<dim3(256), dim3(256), 0, stream>>>(cv, w2, bloc, bmask, out);
}

// Round 2
// 266.354 us; speedup vs baseline: 1.2747x; 1.2747x over previous
//
#include <hip/hip_runtime.h>

typedef __attribute__((ext_vector_type(4))) float f32x4;
typedef __attribute__((ext_vector_type(4))) unsigned int u32x4;
typedef __attribute__((ext_vector_type(8))) unsigned short u16x8;
typedef __attribute__((ext_vector_type(8))) __bf16 bf16x8;

#define DEVFN static __device__ __forceinline__

DEVFN unsigned short f2b(float f) {
  unsigned u = __builtin_bit_cast(unsigned, f);
  u += 0x7fffu + ((u >> 16) & 1u);
  return (unsigned short)(u >> 16);
}
DEVFN float b2f(unsigned short h) {
  unsigned u = ((unsigned)h) << 16;
  return __builtin_bit_cast(float, u);
}
DEVFN float sigf(float x) { return 1.0f / (1.0f + __expf(-x)); }

// ---------------- workspace layout (bytes) ----------------
#define XP_BYTES (16ull*66*66*288*2)   // padded bf16 NHWC input
#define WT_BYTES (512ull*2688*2)       // conv weights [o][kpad], kpad=2688 (9*288 + 96 phantom zeros)
#define W2_BYTES (64ull*512*2)         // head weights [o(64)][k(512)]
#define CV_BYTES (65536ull*512*2)      // RAW conv output (pre-BN), [pixel][512] bf16
#define PS_BYTES (512ull*256*2*4)      // BN partials [ch 512][mt 256]{sum,sumsq}
#define XP_OFF 0ull
#define WT_OFF (XP_OFF + XP_BYTES)
#define W2_OFF (WT_OFF + WT_BYTES)
#define CV_OFF (W2_OFF + W2_BYTES)
#define PS_OFF (CV_OFF + CV_BYTES)
#define SB_OFF (PS_OFF + PS_BYTES)     // sb: [0..511]=scale, [512..1023]=bias

#define GLOAD16(gp, lp) __builtin_amdgcn_global_load_lds( \
    (__attribute__((address_space(1))) void*)(gp),        \
    (__attribute__((address_space(3))) void*)(lp), 16, 0, 0)

#define BAR()  do { __builtin_amdgcn_s_barrier(); __builtin_amdgcn_sched_barrier(0); } while (0)
#define WLG0() do { asm volatile("s_waitcnt lgkmcnt(0)" ::: "memory"); __builtin_amdgcn_sched_barrier(0); } while (0)

// ---------------- prep kernels ----------------
// zero only border cells (y==0||y==65||x==0||x==65), all 288 ch
__global__ void k_zero_border(unsigned short* __restrict__ xp) {
  int idx = blockIdx.x * 256 + threadIdx.x;      // 16*260*36 = 149760 chunks of 16B
  if (idx >= 149760) return;
  int cell_i = idx / 36, u = idx - cell_i * 36;
  int b = cell_i / 260, r = cell_i - b * 260;
  int y, x;
  if (r < 66) { y = 0; x = r; }
  else if (r < 132) { y = 65; x = r - 66; }
  else if (r < 196) { y = r - 131; x = 0; }
  else { y = r - 195; x = 65; }
  int cell = (b * 66 + y) * 66 + x;
  *(u32x4*)((unsigned char*)xp + (size_t)cell * 576 + u * 16) = (u32x4){0u, 0u, 0u, 0u};
}

// input1 (16,256,64,64) f32 -> Xp[b][y+1][x+1][c] bf16 (c<256)
__global__ void k_pack_in(const float* __restrict__ in1, unsigned short* __restrict__ xp) {
  __shared__ float lt[32][65];
  int tid = threadIdx.x;
  int bid = blockIdx.x;
  int cg = bid & 7, y = (bid >> 3) & 63, b = bid >> 9;
  int x = tid & 63, cr = tid >> 6;
#pragma unroll
  for (int i = 0; i < 8; ++i) {
    int cl = i * 4 + cr;
    lt[cl][x] = in1[(((size_t)(b * 256 + cg * 32 + cl) * 64 + y) * 64) + x];
  }
  __syncthreads();
  int xx = tid >> 2, ch = tid & 3;
  u16x8 v;
#pragma unroll
  for (int j = 0; j < 8; ++j) v[j] = f2b(lt[ch * 8 + j][xx]);
  size_t base = ((size_t)((b * 66 + y + 1) * 66 + xx + 1)) * 288 + cg * 32 + ch * 8;
  *(u16x8*)(xp + base) = v;
}

// grid channels + ch-pad: writes ch 256..287 = [x, y, 0 x30]
__global__ void k_pack_grid(unsigned short* __restrict__ xp) {
  int pid = blockIdx.x * 256 + threadIdx.x;
  int b = pid >> 12, pi = pid & 4095, y = pi >> 6, x = pi & 63;
  unsigned short* p = xp + ((size_t)((b * 66 + y + 1) * 66 + x + 1)) * 288 + 256;
  u16x8 v0 = (u16x8){0, 0, 0, 0, 0, 0, 0, 0};
  v0[0] = f2b((float)x); v0[1] = f2b((float)y);
  *(u16x8*)p = v0;
  u16x8 z = (u16x8){0, 0, 0, 0, 0, 0, 0, 0};
  *(u16x8*)(p + 8) = z; *(u16x8*)(p + 16) = z; *(u16x8*)(p + 24) = z;
}

// w_conv (512,258,3,3) -> wt[o][kpad=2688], k = tap*288 + ci; phantom (k>=2592) and ci>=258 -> 0
__global__ void k_pack_w(const float* __restrict__ wc, unsigned short* __restrict__ wt) {
  int idx = blockIdx.x * 256 + threadIdx.x;     // 512*2688 = 1376256
  if (idx >= 1376256) return;
  int o = idx / 2688, k = idx - o * 2688;
  int tap = k / 288, ci = k - tap * 288;
  float v = (tap < 9 && ci < 258) ? wc[(size_t)(o * 258 + ci) * 9 + tap] : 0.f;
  wt[idx] = f2b(v);
}

// head weights: o<10 w_loc, 10..57 w_mask, pad to 64
__global__ void k_pack_w2(const float* __restrict__ wl, const float* __restrict__ wm,
                          unsigned short* __restrict__ w2) {
  int idx = blockIdx.x * 256 + threadIdx.x;  // 32768
  int o = idx >> 9, k = idx & 511;
  float v = 0.f;
  if (o < 10) v = wl[o * 512 + k];
  else if (o < 58) v = wm[(o - 10) * 512 + k];
  w2[idx] = f2b(v);
}

// ---------------- conv: 256x256 tile, BK=64, 8-phase (per-tile 4-phase x 42 tiles) ----------------
// K = 42 tiles of 64 = 2688 = 9 taps * 288ch + 96 phantom (zero weights).
// LDS 128KB: buf{0,1} x 64KB; each buf: A[256 rows][64k] (32KB) + B[256 o][64k] (32KB).
// XOR-unit swizzle: slot(row,u) holds global unit u^(row&7); staged via pre-swizzled global src.
__global__ __launch_bounds__(512, 2) void k_conv8(const unsigned short* __restrict__ xp,
                                                  const unsigned short* __restrict__ wt,
                                                  unsigned short* __restrict__ cv,
                                                  float* __restrict__ ps) {
  extern __shared__ char smem[];
  int tid = threadIdx.x, lane = tid & 63, wv = tid >> 6;
  int wm = wv >> 2, wn = wv & 3;                  // 2M x 4N waves; per-wave out 128px x 64ch
  int bid = blockIdx.x;
  int nt = bid >> 8, mt0 = bid & 255;
  int mt = (mt0 & 7) * 32 + (mt0 >> 3);           // XCD-chunked m-tiles
  int n0 = nt * 256;
  int pix0 = mt * 256;
  int b = pix0 >> 12, pi0 = pix0 & 4095;

  // ---- staging constants ----
  int srow = tid >> 3;                            // 0..63
  int ug = (tid & 7) ^ (srow & 7);                // pre-swizzled global k-unit
  unsigned cellB[4], oB[4];
#pragma unroll
  for (int j = 0; j < 4; ++j) {
    int pi = pi0 + srow + 64 * j;
    int yy = pi >> 6, xx = pi & 63;
    cellB[j] = (unsigned)((b * 66 + yy) * 66 + xx) * 576u;   // bytes
    oB[j] = (unsigned)(n0 + srow + 64 * j) * 5376u;          // 2688*2 bytes
  }

  auto stageA = [&](int tau, int h) {
    int buf = tau & 1;
    unsigned k = (unsigned)tau * 64u + (unsigned)ug * 8u;
    unsigned tap = k / 288u; if (tap > 8u) tap = 8u;
    unsigned ci = k - tap * 288u;
    unsigned dy = tap / 3u, dx = tap - dy * 3u;
    unsigned off = ((dy * 66u + dx) * 288u + ci) * 2u;
    const unsigned char* g = (const unsigned char*)xp;
    char* l = smem + buf * 65536 + h * 16384;
    GLOAD16(g + cellB[h * 2] + off, l + tid * 16);
    GLOAD16(g + cellB[h * 2 + 1] + off, l + 8192 + tid * 16);
  };
  auto stageB = [&](int tau, int h) {
    int buf = tau & 1;
    unsigned k2 = ((unsigned)tau * 64u + (unsigned)ug * 8u) * 2u;
    const unsigned char* g = (const unsigned char*)wt;
    char* l = smem + buf * 65536 + 32768 + h * 16384;
    GLOAD16(g + oB[h * 2] + k2, l + tid * 16);
    GLOAD16(g + oB[h * 2 + 1] + k2, l + 8192 + tid * 16);
  };

  // ---- fragment read constants ----
  unsigned aoffb[8], boffb[4];
#pragma unroll
  for (int mf = 0; mf < 8; ++mf) aoffb[mf] = (unsigned)(wm * 128 + mf * 16 + (lane & 15)) * 128u;
#pragma unroll
  for (int nf = 0; nf < 4; ++nf) boffb[nf] = 32768u + (unsigned)(wn * 64 + nf * 16 + (lane & 15)) * 128u;
  int ko = (lane >> 4) & 3, xm = lane & 7;
  unsigned un[2];
#pragma unroll
  for (int kk = 0; kk < 2; ++kk) un[kk] = (unsigned)(((kk * 4 + ko) ^ xm) * 16);

  f32x4 acc[8][4];
#pragma unroll
  for (int i = 0; i < 8; ++i)
#pragma unroll
    for (int j = 0; j < 4; ++j) acc[i][j] = (f32x4){0.f, 0.f, 0.f, 0.f};

  // ---- prologue: tile0 fully + tile1 B halves ----
  stageB(0, 0); stageB(0, 1); stageA(0, 0); stageA(0, 1); stageB(1, 0); stageB(1, 1);
  asm volatile("s_waitcnt vmcnt(4)" ::: "memory");
  __builtin_amdgcn_sched_barrier(0);
  BAR();

  bf16x8 af[4][2], bf[4][2];
#pragma unroll 1
  for (int tau = 0; tau < 42; ++tau) {
    bool sA = tau < 41, sB = tau < 40;
    const char* base = smem + (tau & 1) * 65536;
    // ---- ph0: read A[qm0] + B[0,1]; stage (tau+1).A0; MFMA q(0,0)
#pragma unroll
    for (int kk = 0; kk < 2; ++kk) {
#pragma unroll
      for (int m2 = 0; m2 < 4; ++m2) af[m2][kk] = *(const bf16x8*)(base + aoffb[m2] + un[kk]);
#pragma unroll
      for (int n2 = 0; n2 < 2; ++n2) bf[n2][kk] = *(const bf16x8*)(base + boffb[n2] + un[kk]);
    }
    if (sA) stageA(tau + 1, 0);
    BAR(); WLG0();
    __builtin_amdgcn_s_setprio(1);
#pragma unroll
    for (int kk = 0; kk < 2; ++kk)
#pragma unroll
      for (int m2 = 0; m2 < 4; ++m2)
#pragma unroll
        for (int n2 = 0; n2 < 2; ++n2)
          acc[m2][n2] = __builtin_amdgcn_mfma_f32_16x16x32_bf16(af[m2][kk], bf[n2][kk], acc[m2][n2], 0, 0, 0);
    __builtin_amdgcn_s_setprio(0);
    BAR();
    // ---- ph1: read B[2,3]; stage (tau+1).A1; MFMA q(0,1)
#pragma unroll
    for (int kk = 0; kk < 2; ++kk)
#pragma unroll
      for (int n2 = 2; n2 < 4; ++n2) bf[n2][kk] = *(const bf16x8*)(base + boffb[n2] + un[kk]);
    if (sA) stageA(tau + 1, 1);
    BAR(); WLG0();
    __builtin_amdgcn_s_setprio(1);
#pragma unroll
    for (int kk = 0; kk < 2; ++kk)
#pragma unroll
      for (int m2 = 0; m2 < 4; ++m2)
#pragma unroll
        for (int n2 = 2; n2 < 4; ++n2)
          acc[m2][n2] = __builtin_amdgcn_mfma_f32_16x16x32_bf16(af[m2][kk], bf[n2][kk], acc[m2][n2], 0, 0, 0);
    __builtin_amdgcn_s_setprio(0);
    BAR();
    // ---- ph2: read A[qm1]; stage (tau+2).B0; MFMA q(1,0)
#pragma unroll
    for (int kk = 0; kk < 2; ++kk)
#pragma unroll
      for (int m2 = 0; m2 < 4; ++m2) af[m2][kk] = *(const bf16x8*)(base + aoffb[4 + m2] + un[kk]);
    if (sB) stageB(tau + 2, 0);
    BAR(); WLG0();
    __builtin_amdgcn_s_setprio(1);
#pragma unroll
    for (int kk = 0; kk < 2; ++kk)
#pragma unroll
      for (int m2 = 0; m2 < 4; ++m2)
#pragma unroll
        for (int n2 = 0; n2 < 2; ++n2)
          acc[4 + m2][n2] = __builtin_amdgcn_mfma_f32_16x16x32_bf16(af[m2][kk], bf[n2][kk], acc[4 + m2][n2], 0, 0, 0);
    __builtin_amdgcn_s_setprio(0);
    BAR();
    // ---- ph3: stage (tau+2).B1; counted vmcnt; MFMA q(1,1)
    if (sB) stageB(tau + 2, 1);
    if (tau < 40) { asm volatile("s_waitcnt vmcnt(4)" ::: "memory"); __builtin_amdgcn_sched_barrier(0); }
    else if (tau == 40) { asm volatile("s_waitcnt vmcnt(0)" ::: "memory"); __builtin_amdgcn_sched_barrier(0); }
    BAR();
    __builtin_amdgcn_s_setprio(1);
#pragma unroll
    for (int kk = 0; kk < 2; ++kk)
#pragma unroll
      for (int m2 = 0; m2 < 4; ++m2)
#pragma unroll
        for (int n2 = 2; n2 < 4; ++n2)
          acc[4 + m2][n2] = __builtin_amdgcn_mfma_f32_16x16x32_bf16(af[m2][kk], bf[n2][kk], acc[4 + m2][n2], 0, 0, 0);
    __builtin_amdgcn_s_setprio(0);
    BAR();
  }

  // ---- epilogue 1: raw conv -> cv (bf16), via LDS repack (XOR-4 store swizzle) ----
  unsigned short* l16 = (unsigned short*)smem;
#pragma unroll
  for (int mf = 0; mf < 8; ++mf)
#pragma unroll
    for (int nf = 0; nf < 4; ++nf)
#pragma unroll
      for (int r = 0; r < 4; ++r) {
        int row = wm * 128 + mf * 16 + (lane >> 4) * 4 + r;
        int col = wn * 64 + nf * 16 + (lane & 15);
        int colx = col ^ (((row >> 2) & 3) << 3);
        l16[row * 256 + colx] = f2b(acc[mf][nf][r]);
      }
  __syncthreads();
#pragma unroll
  for (int i = 0; i < 16; ++i) {
    int q = tid + 512 * i;                 // 8192 chunks of 16B
    int prow = q >> 5, c16 = q & 31;
    int c16g = c16 ^ ((prow >> 2) & 3);
    *(u16x8*)(cv + ((size_t)(pix0 + prow) * 512 + n0 + c16g * 8)) = *(const u16x8*)(l16 + q * 8);
  }
  __syncthreads();

  // ---- epilogue 2: BN partial stats from f32 acc ----
  float* lf = (float*)smem;
  float sv[4], qv[4];
#pragma unroll
  for (int nf = 0; nf < 4; ++nf) {
    float s = 0.f, q = 0.f;
#pragma unroll
    for (int mf = 0; mf < 8; ++mf)
#pragma unroll
      for (int r = 0; r < 4; ++r) { float v = acc[mf][nf][r]; s += v; q += v * v; }
    s += __shfl_xor(s, 16); s += __shfl_xor(s, 32);
    q += __shfl_xor(q, 16); q += __shfl_xor(q, 32);
    sv[nf] = s; qv[nf] = q;
  }
  if (lane < 16) {
#pragma unroll
    for (int nf = 0; nf < 4; ++nf) {
      int ch = wn * 64 + nf * 16 + lane;
      lf[wm * 256 + ch] = sv[nf];
      lf[512 + wm * 256 + ch] = qv[nf];
    }
  }
  __syncthreads();
  if (tid < 256) {
    float S = lf[tid] + lf[256 + tid];
    float Q = lf[512 + tid] + lf[768 + tid];
    ((float2*)ps)[(size_t)(n0 + tid) * 256 + mt] = make_float2(S, Q);
  }
}

// ---------------- BN finalize: scale/bias ----------------
__global__ void k_bnfinal(const float* __restrict__ ps, const float* __restrict__ gamma,
                          const float* __restrict__ beta, float* __restrict__ sb) {
  int c = threadIdx.x;  // 512
  const float2* p2 = (const float2*)ps;
  float s = 0.f, q = 0.f;
  for (int mtv = 0; mtv < 256; ++mtv) { float2 v = p2[(size_t)c * 256 + mtv]; s += v.x; q += v.y; }
  float mean = s * (1.0f / 65536.0f);
  float var = q * (1.0f / 65536.0f) - mean * mean;
  float sc = gamma[c] / sqrtf(var + 1e-5f);
  sb[c] = sc;
  sb[512 + c] = beta[c] - mean * sc;
}

// ---------------- head: BN+leaky fused A-load, 256px x 64out GEMM (K=512) + decode ----------------
__global__ __launch_bounds__(256) void k_head(const unsigned short* __restrict__ cv,
                                              const unsigned short* __restrict__ w2,
                                              const float* __restrict__ bl,
                                              const float* __restrict__ bm,
                                              const float* __restrict__ sb,
                                              float* __restrict__ out) {
  __shared__ float lo[256][59];
  __shared__ float sS[512], sBb[512];
  int tid = threadIdx.x, lane = tid & 63, wv = tid >> 6;
  int pix0 = blockIdx.x * 256;
  sS[tid] = sb[tid]; sS[256 + tid] = sb[256 + tid];
  sBb[tid] = sb[512 + tid]; sBb[256 + tid] = sb[768 + tid];
  __syncthreads();

  f32x4 acc[4][4];
#pragma unroll
  for (int mf = 0; mf < 4; ++mf)
#pragma unroll
    for (int nf = 0; nf < 4; ++nf) acc[mf][nf] = (f32x4){0.f, 0.f, 0.f, 0.f};
  int ko = lane >> 4;

  for (int k0 = 0; k0 < 512; k0 += 32) {
    int c0 = k0 + ko * 8;
    f32x4 sc0 = *(const f32x4*)&sS[c0], sc1 = *(const f32x4*)&sS[c0 + 4];
    f32x4 bo0 = *(const f32x4*)&sBb[c0], bo1 = *(const f32x4*)&sBb[c0 + 4];
    bf16x8 a[4], bg[4];
#pragma unroll
    for (int f = 0; f < 4; ++f) {
      bg[f] = *(const bf16x8*)(w2 + (size_t)(f * 16 + (lane & 15)) * 512 + c0);
      u16x8 raw = *(const u16x8*)(cv + (size_t)(pix0 + wv * 64 + f * 16 + (lane & 15)) * 512 + c0);
      u16x8 av;
#pragma unroll
      for (int j = 0; j < 4; ++j) {
        float v = b2f(raw[j]) * sc0[j] + bo0[j];
        v = (v > 0.f) ? v : 0.1f * v;
        av[j] = f2b(v);
      }
#pragma unroll
      for (int j = 0; j < 4; ++j) {
        float v = b2f(raw[4 + j]) * sc1[j] + bo1[j];
        v = (v > 0.f) ? v : 0.1f * v;
        av[4 + j] = f2b(v);
      }
      a[f] = __builtin_bit_cast(bf16x8, av);
    }
#pragma unroll
    for (int mf = 0; mf < 4; ++mf)
#pragma unroll
      for (int nf = 0; nf < 4; ++nf)
        acc[mf][nf] = __builtin_amdgcn_mfma_f32_16x16x32_bf16(a[mf], bg[nf], acc[mf][nf], 0, 0, 0);
  }

  float bias[4]; int colv[4];
#pragma unroll
  for (int nf = 0; nf < 4; ++nf) {
    int col = nf * 16 + (lane & 15);
    colv[nf] = col;
    bias[nf] = (col < 10) ? bl[col] : ((col < 58) ? bm[col - 10] : 0.f);
  }
#pragma unroll
  for (int mf = 0; mf < 4; ++mf)
#pragma unroll
    for (int nf = 0; nf < 4; ++nf)
#pragma unroll
      for (int r = 0; r < 4; ++r) {
        int row = wv * 64 + mf * 16 + (lane >> 4) * 4 + r;
        if (colv[nf] < 58) lo[row][colv[nf]] = acc[mf][nf][r] + bias[nf];
      }
  __syncthreads();

  // ---- decode: one thread = one pixel ----
  int pix = pix0 + tid;
  int b = pix >> 12, pi = pix & 4095;
  int yi = pi >> 6, xi = pi & 63;
  float X = (float)xi, Y = (float)yi;
  const float* O = lo[tid];

  float* outP = out;
  float* outB = out + 655360;
  float* outOL = out + 1572864;
  float* outOC = out + 2752512;
  float* outML = out + 3932160;
  float* outMC = out + 4521984;
  float* outWC = out + 5111808;
  float* outOD = out + 5636096;

  float pr[10];
#pragma unroll
  for (int i = 0; i < 10; ++i) { pr[i] = O[i]; outP[(size_t)pix * 10 + i] = pr[i]; }
  const float st = 8.f, ist = 0.125f;
  float l0 = pr[0] * pr[0] * st, l1 = pr[1] * pr[1] * st;
  float l2 = pr[2] * pr[2] * st, l3 = pr[3] * pr[3] * st;
  float cx = X * st + 4.f, cy = Y * st + 4.f;
  float xmin = cx - l3, ymin = cy - l0, xmax = cx + l1, ymax = cy + l2;
  float w = l1 + l3, h = l0 + l2;
  float xc = 0.5f * (xmax + xmin), yc = 0.5f * (ymax + ymin);
  float r = sigf(pr[8]);
  float maskr = (r > 0.9f) ? 0.f : 1.f;
  float s0 = sigf(pr[4]) * maskr, s1 = sigf(pr[5]) * maskr;
  float s2 = sigf(pr[6]) * maskr, s3 = sigf(pr[7]) * maskr;
  float conf = sigf(pr[9]);
  {
    size_t bo = (size_t)pix * 14;
    outB[bo + 0] = xc; outB[bo + 1] = yc; outB[bo + 2] = w; outB[bo + 3] = h;
    outB[bo + 4] = s0; outB[bo + 5] = s1; outB[bo + 6] = s2; outB[bo + 7] = s3;
    outB[bo + 8] = r;  outB[bo + 9] = l0; outB[bo + 10] = l1; outB[bo + 11] = l2;
    outB[bo + 12] = l3; outB[bo + 13] = conf;
  }
  float x1 = xmin + s0 * w, x7 = xmax - s2 * w;
  float y5 = ymin + s1 * h, y3 = ymax - s3 * h;
  float xob = 0.5f * (x1 + x7), yob = 0.5f * (y5 + y3);
  float ov[22];
#pragma unroll
  for (int j = 0; j < 22; ++j) ov[j] = sigf(O[28 + j]);
  float eps = ceilf(0.01f * w);
  bool c0 = x1 < xmin + eps;
  float xp0 = c0 ? x1 : xmin + ov[0] * (x1 - xmin);
  float yp0 = c0 ? ymin + ov[0] * (y3 - ymin)
                 : (y3 - ymin) / (xmin - x1 + 1e-8f) * (xp0 - x1) + ymin;
  bool c2 = x1 > xmax - eps;
  float xp2 = c2 ? x1 : xmax - ov[1] * (xmax - x1);
  float yp2 = c2 ? ymin + ov[1] * (y5 - ymin)
                 : (y5 - ymin) / (xmax - x1 + 1e-8f) * (xp2 - x1) + ymin;
  bool c6 = x7 < xmin + eps;
  float xp6 = c6 ? x7 : xmin + ov[2] * (x7 - xmin);
  float yp6 = c6 ? ymax - ov[2] * (ymax - y3)
                 : (y3 - ymax) / (xmin - x7 + 1e-8f) * (xp6 - x7) + ymax;
  bool c8c = x7 > xmax - eps;
  float xp8 = c8c ? x7 : xmax - ov[3] * (xmax - x7);
  float yp8 = c8c ? ymax - ov[3] * (ymax - y5)
                  : (y5 - ymax) / (xmax - x7 + 1e-8f) * (xp8 - x7) + ymax;

  size_t olb = ((size_t)b * 18) * 4096 + pi;
  outOL[olb + 0 * 4096] = yp0 * ist + 1.f - Y;
  outOL[olb + 1 * 4096] = xp0 * ist + 1.f - X;
  outOL[olb + 2 * 4096] = ymin * ist + 1.f - Y;
  outOL[olb + 3 * 4096] = x1 * ist - X;
  outOL[olb + 4 * 4096] = yp2 * ist + 1.f - Y;
  outOL[olb + 5 * 4096] = xp2 * ist - 1.f - X;
  outOL[olb + 6 * 4096] = y3 * ist - Y;
  outOL[olb + 7 * 4096] = xmin * ist + 1.f - X;
  outOL[olb + 8 * 4096] = 0.f;
  outOL[olb + 9 * 4096] = 0.f;
  outOL[olb + 10 * 4096] = y5 * ist - Y;
  outOL[olb + 11 * 4096] = xmax * ist - 1.f - X;
  outOL[olb + 12 * 4096] = yp6 * ist - 1.f - Y;
  outOL[olb + 13 * 4096] = xp6 * ist + 1.f - X;
  outOL[olb + 14 * 4096] = ymax * ist - 1.f - Y;
  outOL[olb + 15 * 4096] = x7 * ist - X;
  outOL[olb + 16 * 4096] = yp8 * ist - 1.f - Y;
  outOL[olb + 17 * 4096] = xp8 * ist - 1.f - X;

  float A1 = x1 - xmax, B1 = ymin - y5, A2 = xmin - x7, B2 = y3 - ymax;
  float width = 0.5f * (sqrtf(A1 * A1 + B1 * B1) + sqrtf(A2 * A2 + B2 * B2));
  float C1 = xmin - x1, D1 = y3 - ymin, C2 = x7 - xmax, D2 = ymax - y5;
  float height = 0.5f * (sqrtf(C1 * C1 + D1 * D1) + sqrtf(C2 * C2 + D2 * D2));
  float ang = 0.5f * (atanf((y5 - ymin) / (xmax - x1 + 1e-4f)) +
                      atanf((ymax - y3) / (x7 - xmin + 1e-4f)));
  float ca = cosf(ang), sa = sinf(ang);
  const float DD = 0.70710678118654752f;
  const float dyc[9] = {DD, 1.f, DD, 0.f, 0.f, 0.f, -DD, -1.f, -DD};
  const float dxc[9] = {DD, 0.f, -DD, 1.f, 0.f, -1.f, DD, 0.f, -DD};
  size_t ocb = ((size_t)b * 18) * 4096 + pi;
  size_t odb = (size_t)pix * 18;
#pragma unroll
  for (int k = 0; k < 9; ++k) {
    float xd = xob - 0.5f * width + ov[13 + k] * width;
    float yd = yob - 0.5f * height + ov[4 + k] * height;
    float ddx = xd - xob, ddy = yd - yob;
    float xd0 = ca * ddx - sa * ddy + xob;
    float xdc = fminf(fmaxf(xd0, xmin), xmax);
    float yd0 = sa * ddx + ca * ddy + yob;
    float ydc = fminf(fmaxf(yd0, ymin), ymax);
    outOC[ocb + (size_t)(2 * k) * 4096] = ydc * ist + dyc[k] - Y;
    outOC[ocb + (size_t)(2 * k + 1) * 4096] = xdc * ist + dxc[k] - X;
    outOD[odb + k] = xdc;
    outOD[odb + 9 + k] = ydc;
  }
  size_t mlb = ((size_t)b * 9) * 4096 + pi;
#pragma unroll
  for (int k = 0; k < 9; ++k) outML[mlb + (size_t)k * 4096] = sigf(O[10 + k]);
#pragma unroll
  for (int k = 0; k < 9; ++k) outMC[mlb + (size_t)k * 4096] = sigf(O[19 + k]);
  float v8[8], mx = -1e30f;
#pragma unroll
  for (int k = 0; k < 8; ++k) { v8[k] = O[50 + k]; mx = fmaxf(mx, v8[k]); }
  float sm = 0.f;
#pragma unroll
  for (int k = 0; k < 8; ++k) { v8[k] = __expf(v8[k] - mx); sm += v8[k]; }
  float inv = 1.f / sm;
  size_t wcb = ((size_t)b * 8) * 4096 + pi;
#pragma unroll
  for (int k = 0; k < 8; ++k) outWC[wcb + (size_t)k * 4096] = v8[k] * inv;
}

// ---------------- launch ----------------
extern "C" void kernel_launch(void* const* d_in, const int* in_sizes, int n_in,
                              void* d_out, int out_size, void* d_ws, size_t ws_size,
                              hipStream_t stream) {
  const float* in1 = (const float*)d_in[0];
  const float* wconv = (const float*)d_in[1];
  const float* gamma = (const float*)d_in[2];
  const float* beta = (const float*)d_in[3];
  const float* wloc = (const float*)d_in[4];
  const float* bloc = (const float*)d_in[5];
  const float* wmask = (const float*)d_in[6];
  const float* bmask = (const float*)d_in[7];
  unsigned char* ws = (unsigned char*)d_ws;
  unsigned short* xp = (unsigned short*)(ws + XP_OFF);
  unsigned short* wt = (unsigned short*)(ws + WT_OFF);
  unsigned short* w2 = (unsigned short*)(ws + W2_OFF);
  unsigned short* cv = (unsigned short*)(ws + CV_OFF);
  float* ps = (float*)(ws + PS_OFF);
  float* sb = (float*)(ws + SB_OFF);
  float* out = (float*)d_out;

  (void)hipFuncSetAttribute(reinterpret_cast<const void*>(k_conv8),
                            hipFuncAttributeMaxDynamicSharedMemorySize, 131072);

  k_zero_border<<<dim3(585), dim3(256), 0, stream>>>(xp);
  k_pack_in<<<dim3(8192), dim3(256), 0, stream>>>(in1, xp);
  k_pack_grid<<<dim3(256), dim3(256), 0, stream>>>(xp);
  k_pack_w<<<dim3(5376), dim3(256), 0, stream>>>(wconv, wt);
  k_pack_w2<<<dim3(128), dim3(256), 0, stream>>>(wloc, wmask, w2);
  k_conv8<<<dim3(512), dim3(512), 131072, stream>>>(xp, wt, cv, ps);
  k_bnfinal<<<dim3(1), dim3(512), 0, stream>>>(ps, gamma, beta, sb);
  k_head<<<dim3(256), dim3(256), 0, stream>>>(cv, w2, bloc, bmask, sb, out);
}

// Round 3
// 215.311 us; speedup vs baseline: 1.5769x; 1.2371x over previous
//
#include <hip/hip_runtime.h>

typedef __attribute__((ext_vector_type(4))) float f32x4;
typedef __attribute__((ext_vector_type(4))) unsigned int u32x4;
typedef __attribute__((ext_vector_type(8))) unsigned short u16x8;
typedef __attribute__((ext_vector_type(8))) __bf16 bf16x8;

#define DEVFN static __device__ __forceinline__

DEVFN unsigned short f2b(float f) {
  unsigned u = __builtin_bit_cast(unsigned, f);
  u += 0x7fffu + ((u >> 16) & 1u);
  return (unsigned short)(u >> 16);
}
DEVFN float b2f(unsigned short h) {
  unsigned u = ((unsigned)h) << 16;
  return __builtin_bit_cast(float, u);
}
DEVFN float sigf(float x) { return 1.0f / (1.0f + __expf(-x)); }

// ---------------- geometry ----------------
// Channel stride CS=264 (258 real + 6 pad). K-layout: 3 dy-groups of 800
// (3 horizontal taps contiguous = 792, + 8 phantom), K=2400, padded to 2432 (38 tiles of 64).
#define CS 264
#define KPAD 2432
#define NTILE 38

// ---------------- workspace layout (bytes) ----------------
#define XP_BYTES (16ull*66*66*CS*2)    // padded bf16 NHWC input
#define WT_BYTES (512ull*KPAD*2)       // conv weights [o][kpad]
#define W2_BYTES (64ull*512*2)         // head weights [o(64)][k(512)]
#define CV_BYTES (65536ull*512*2)      // RAW conv output (pre-BN), [pixel][512] bf16
#define PS_BYTES (512ull*256*2*4)      // BN partials [ch 512][mt 256]{sum,sumsq}
#define XP_OFF 0ull
#define WT_OFF (XP_OFF + XP_BYTES)
#define W2_OFF (WT_OFF + WT_BYTES)
#define CV_OFF (W2_OFF + W2_BYTES)
#define PS_OFF (CV_OFF + CV_BYTES)
#define SB_OFF (PS_OFF + PS_BYTES)     // sb: [0..511]=scale, [512..1023]=bias

#define GLOAD16(gp, lp) __builtin_amdgcn_global_load_lds( \
    (__attribute__((address_space(1))) void*)(gp),        \
    (__attribute__((address_space(3))) void*)(lp), 16, 0, 0)

#define BAR()  do { __builtin_amdgcn_s_barrier(); __builtin_amdgcn_sched_barrier(0); } while (0)
#define WLG0() do { asm volatile("s_waitcnt lgkmcnt(0)" ::: "memory"); __builtin_amdgcn_sched_barrier(0); } while (0)

// ---------------- merged prep kernel ----------------
// ranges: [0,537) zero-border | [537,793) grid ch | [793,5657) pack conv w | [5657,5785) pack head w
__global__ void k_prep(const float* __restrict__ wc, const float* __restrict__ wl,
                       const float* __restrict__ wm, unsigned short* __restrict__ xp,
                       unsigned short* __restrict__ wt, unsigned short* __restrict__ w2) {
  int bid = blockIdx.x, tid = threadIdx.x;
  if (bid < 537) {                         // border cells: 16*260 cells * 33 16B-units
    int idx = bid * 256 + tid;
    if (idx >= 137280) return;
    int cell_i = idx / 33, u = idx - cell_i * 33;
    int b = cell_i / 260, r = cell_i - b * 260;
    int y, x;
    if (r < 66) { y = 0; x = r; }
    else if (r < 132) { y = 65; x = r - 66; }
    else if (r < 196) { y = r - 131; x = 0; }
    else { y = r - 195; x = 65; }
    int cell = (b * 66 + y) * 66 + x;
    *(u32x4*)((unsigned char*)xp + (size_t)cell * (CS * 2) + u * 16) = (u32x4){0u, 0u, 0u, 0u};
  } else if (bid < 793) {                  // grid channels 256,257 + pad 258..263
    int pid = (bid - 537) * 256 + tid;
    int b = pid >> 12, pi = pid & 4095, y = pi >> 6, x = pi & 63;
    u16x8 v0 = (u16x8){0, 0, 0, 0, 0, 0, 0, 0};
    v0[0] = f2b((float)x); v0[1] = f2b((float)y);
    *(u16x8*)(xp + ((size_t)((b * 66 + y + 1) * 66 + x + 1)) * CS + 256) = v0;
  } else if (bid < 5657) {                 // conv weights: 512*2432 = 1245184
    int idx = (bid - 793) * 256 + tid;
    int o = idx / KPAD, k = idx - o * KPAD;
    int dy = k / 800, t = k - dy * 800;
    int dx = t / CS, ci = t - dx * CS;
    float v = (dy < 3 && dx < 3 && ci < 258) ? wc[(size_t)(o * 258 + ci) * 9 + dy * 3 + dx] : 0.f;
    wt[idx] = f2b(v);
  } else {                                 // head weights: 32768
    int idx = (bid - 5657) * 256 + tid;
    int o = idx >> 9, k = idx & 511;
    float v = 0.f;
    if (o < 10) v = wl[o * 512 + k];
    else if (o < 58) v = wm[(o - 10) * 512 + k];
    w2[idx] = f2b(v);
  }
}

// input1 (16,256,64,64) f32 -> Xp[b][y+1][x+1][c] bf16 (c<256)
__global__ void k_pack_in(const float* __restrict__ in1, unsigned short* __restrict__ xp) {
  __shared__ float lt[32][65];
  int tid = threadIdx.x;
  int bid = blockIdx.x;
  int cg = bid & 7, y = (bid >> 3) & 63, b = bid >> 9;
  int x = tid & 63, cr = tid >> 6;
#pragma unroll
  for (int i = 0; i < 8; ++i) {
    int cl = i * 4 + cr;
    lt[cl][x] = in1[(((size_t)(b * 256 + cg * 32 + cl) * 64 + y) * 64) + x];
  }
  __syncthreads();
  int xx = tid >> 2, ch = tid & 3;
  u16x8 v;
#pragma unroll
  for (int j = 0; j < 8; ++j) v[j] = f2b(lt[ch * 8 + j][xx]);
  size_t base = ((size_t)((b * 66 + y + 1) * 66 + xx + 1)) * CS + cg * 32 + ch * 8;
  *(u16x8*)(xp + base) = v;
}

// ---------------- conv: 256x256 tile, BK=64, 4-phase x 38 K-tiles ----------------
// LDS 128KB: buf{0,1} x 64KB; each buf: A[256 rows][64k] (32KB) + B[256 o][64k] (32KB).
// XOR-unit swizzle: slot(row,u) holds global unit u^(row&7); staged via pre-swizzled global src.
__global__ __launch_bounds__(512, 2) void k_conv8(const unsigned short* __restrict__ xp,
                                                  const unsigned short* __restrict__ wt,
                                                  unsigned short* __restrict__ cv,
                                                  float* __restrict__ ps) {
  extern __shared__ char smem[];
  int tid = threadIdx.x, lane = tid & 63, wv = tid >> 6;
  int wm = wv >> 2, wn = wv & 3;                  // 2M x 4N waves; per-wave out 128px x 64ch
  int bid = blockIdx.x;
  // XCD-paired mapping: XCD x runs both nt of mt-chunk [x*32, x*32+32)
  int xcd = bid & 7, j = bid >> 3;
  int nt = j & 1;
  int mt = xcd * 32 + (j >> 1);
  int n0 = nt * 256;
  int pix0 = mt * 256;
  int b = pix0 >> 12, pi0 = pix0 & 4095;

  // ---- staging constants ----
  int srow = tid >> 3;                            // 0..63
  int ug = (tid & 7) ^ (srow & 7);                // pre-swizzled global k-unit
  unsigned cellB[4], oB[4];
#pragma unroll
  for (int jj = 0; jj < 4; ++jj) {
    int pi = pi0 + srow + 64 * jj;
    int yy = pi >> 6, xx = pi & 63;
    cellB[jj] = (unsigned)((b * 66 + yy) * 66 + xx) * (CS * 2);  // base = input (y-1, x-1)
    oB[jj] = (unsigned)(n0 + srow + 64 * jj) * (KPAD * 2);
  }

  auto stageA = [&](int tau, int h) {
    int buf = tau & 1;
    unsigned k = (unsigned)tau * 64u + (unsigned)ug * 8u;
    unsigned dy = k / 800u;
    unsigned t = k - dy * 800u;
    unsigned off = dy * (66u * CS * 2u) + t * 2u;
    const unsigned char* g = (const unsigned char*)xp;
    char* l = smem + buf * 65536 + h * 16384;
    GLOAD16(g + cellB[h * 2] + off, l + tid * 16);
    GLOAD16(g + cellB[h * 2 + 1] + off, l + 8192 + tid * 16);
  };
  auto stageB = [&](int tau, int h) {
    int buf = tau & 1;
    unsigned k2 = ((unsigned)tau * 64u + (unsigned)ug * 8u) * 2u;
    const unsigned char* g = (const unsigned char*)wt;
    char* l = smem + buf * 65536 + 32768 + h * 16384;
    GLOAD16(g + oB[h * 2] + k2, l + tid * 16);
    GLOAD16(g + oB[h * 2 + 1] + k2, l + 8192 + tid * 16);
  };

  // ---- fragment read constants ----
  unsigned aoffb[8], boffb[4];
#pragma unroll
  for (int mf = 0; mf < 8; ++mf) aoffb[mf] = (unsigned)(wm * 128 + mf * 16 + (lane & 15)) * 128u;
#pragma unroll
  for (int nf = 0; nf < 4; ++nf) boffb[nf] = 32768u + (unsigned)(wn * 64 + nf * 16 + (lane & 15)) * 128u;
  int ko = (lane >> 4) & 3, xm = lane & 7;
  unsigned un[2];
#pragma unroll
  for (int kk = 0; kk < 2; ++kk) un[kk] = (unsigned)(((kk * 4 + ko) ^ xm) * 16);

  f32x4 acc[8][4];
#pragma unroll
  for (int i = 0; i < 8; ++i)
#pragma unroll
    for (int jj = 0; jj < 4; ++jj) acc[i][jj] = (f32x4){0.f, 0.f, 0.f, 0.f};

  // ---- prologue: tile0 fully + tile1 B halves ----
  stageB(0, 0); stageB(0, 1); stageA(0, 0); stageA(0, 1); stageB(1, 0); stageB(1, 1);
  asm volatile("s_waitcnt vmcnt(4)" ::: "memory");
  __builtin_amdgcn_sched_barrier(0);
  BAR();

  bf16x8 af[4][2], bf[4][2];
#pragma unroll 1
  for (int tau = 0; tau < NTILE; ++tau) {
    bool sA = tau < NTILE - 1, sB = tau < NTILE - 2;
    const char* base = smem + (tau & 1) * 65536;
    // ---- ph0: read A[qm0] + B[0,1]; stage (tau+1).A0; MFMA q(0,0)
#pragma unroll
    for (int kk = 0; kk < 2; ++kk) {
#pragma unroll
      for (int m2 = 0; m2 < 4; ++m2) af[m2][kk] = *(const bf16x8*)(base + aoffb[m2] + un[kk]);
#pragma unroll
      for (int n2 = 0; n2 < 2; ++n2) bf[n2][kk] = *(const bf16x8*)(base + boffb[n2] + un[kk]);
    }
    if (sA) stageA(tau + 1, 0);
    BAR(); WLG0();
    __builtin_amdgcn_s_setprio(1);
#pragma unroll
    for (int kk = 0; kk < 2; ++kk)
#pragma unroll
      for (int m2 = 0; m2 < 4; ++m2)
#pragma unroll
        for (int n2 = 0; n2 < 2; ++n2)
          acc[m2][n2] = __builtin_amdgcn_mfma_f32_16x16x32_bf16(af[m2][kk], bf[n2][kk], acc[m2][n2], 0, 0, 0);
    __builtin_amdgcn_s_setprio(0);
    BAR();
    // ---- ph1: read B[2,3]; stage (tau+1).A1; MFMA q(0,1)
#pragma unroll
    for (int kk = 0; kk < 2; ++kk)
#pragma unroll
      for (int n2 = 2; n2 < 4; ++n2) bf[n2][kk] = *(const bf16x8*)(base + boffb[n2] + un[kk]);
    if (sA) stageA(tau + 1, 1);
    BAR(); WLG0();
    __builtin_amdgcn_s_setprio(1);
#pragma unroll
    for (int kk = 0; kk < 2; ++kk)
#pragma unroll
      for (int m2 = 0; m2 < 4; ++m2)
#pragma unroll
        for (int n2 = 2; n2 < 4; ++n2)
          acc[m2][n2] = __builtin_amdgcn_mfma_f32_16x16x32_bf16(af[m2][kk], bf[n2][kk], acc[m2][n2], 0, 0, 0);
    __builtin_amdgcn_s_setprio(0);
    BAR();
    // ---- ph2: read A[qm1]; stage (tau+2).B0; MFMA q(1,0)
#pragma unroll
    for (int kk = 0; kk < 2; ++kk)
#pragma unroll
      for (int m2 = 0; m2 < 4; ++m2) af[m2][kk] = *(const bf16x8*)(base + aoffb[4 + m2] + un[kk]);
    if (sB) stageB(tau + 2, 0);
    BAR(); WLG0();
    __builtin_amdgcn_s_setprio(1);
#pragma unroll
    for (int kk = 0; kk < 2; ++kk)
#pragma unroll
      for (int m2 = 0; m2 < 4; ++m2)
#pragma unroll
        for (int n2 = 0; n2 < 2; ++n2)
          acc[4 + m2][n2] = __builtin_amdgcn_mfma_f32_16x16x32_bf16(af[m2][kk], bf[n2][kk], acc[4 + m2][n2], 0, 0, 0);
    __builtin_amdgcn_s_setprio(0);
    BAR();
    // ---- ph3: stage (tau+2).B1; counted vmcnt; MFMA q(1,1)
    if (sB) stageB(tau + 2, 1);
    if (tau < NTILE - 2) { asm volatile("s_waitcnt vmcnt(4)" ::: "memory"); __builtin_amdgcn_sched_barrier(0); }
    else if (tau == NTILE - 2) { asm volatile("s_waitcnt vmcnt(0)" ::: "memory"); __builtin_amdgcn_sched_barrier(0); }
    BAR();
    __builtin_amdgcn_s_setprio(1);
#pragma unroll
    for (int kk = 0; kk < 2; ++kk)
#pragma unroll
      for (int m2 = 0; m2 < 4; ++m2)
#pragma unroll
        for (int n2 = 2; n2 < 4; ++n2)
          acc[4 + m2][n2] = __builtin_amdgcn_mfma_f32_16x16x32_bf16(af[m2][kk], bf[n2][kk], acc[4 + m2][n2], 0, 0, 0);
    __builtin_amdgcn_s_setprio(0);
    BAR();
  }

  // ---- epilogue 1: raw conv -> cv (bf16), via LDS repack (XOR-4 store swizzle) ----
  unsigned short* l16 = (unsigned short*)smem;
#pragma unroll
  for (int mf = 0; mf < 8; ++mf)
#pragma unroll
    for (int nf = 0; nf < 4; ++nf)
#pragma unroll
      for (int r = 0; r < 4; ++r) {
        int row = wm * 128 + mf * 16 + (lane >> 4) * 4 + r;
        int col = wn * 64 + nf * 16 + (lane & 15);
        int colx = col ^ (((row >> 2) & 3) << 3);
        l16[row * 256 + colx] = f2b(acc[mf][nf][r]);
      }
  __syncthreads();
#pragma unroll
  for (int i = 0; i < 16; ++i) {
    int q = tid + 512 * i;                 // 8192 chunks of 16B
    int prow = q >> 5, c16 = q & 31;
    int c16g = c16 ^ ((prow >> 2) & 3);
    *(u16x8*)(cv + ((size_t)(pix0 + prow) * 512 + n0 + c16g * 8)) = *(const u16x8*)(l16 + q * 8);
  }
  __syncthreads();

  // ---- epilogue 2: BN partial stats from f32 acc ----
  float* lf = (float*)smem;
  float sv[4], qv[4];
#pragma unroll
  for (int nf = 0; nf < 4; ++nf) {
    float s = 0.f, q = 0.f;
#pragma unroll
    for (int mf = 0; mf < 8; ++mf)
#pragma unroll
      for (int r = 0; r < 4; ++r) { float v = acc[mf][nf][r]; s += v; q += v * v; }
    s += __shfl_xor(s, 16); s += __shfl_xor(s, 32);
    q += __shfl_xor(q, 16); q += __shfl_xor(q, 32);
    sv[nf] = s; qv[nf] = q;
  }
  if (lane < 16) {
#pragma unroll
    for (int nf = 0; nf < 4; ++nf) {
      int ch = wn * 64 + nf * 16 + lane;
      lf[wm * 256 + ch] = sv[nf];
      lf[512 + wm * 256 + ch] = qv[nf];
    }
  }
  __syncthreads();
  if (tid < 256) {
    float S = lf[tid] + lf[256 + tid];
    float Q = lf[512 + tid] + lf[768 + tid];
    ((float2*)ps)[(size_t)(n0 + tid) * 256 + mt] = make_float2(S, Q);
  }
}

// ---------------- BN finalize: scale/bias (16 blocks, shfl-reduced) ----------------
__global__ void k_bnfinal(const float* __restrict__ ps, const float* __restrict__ gamma,
                          const float* __restrict__ beta, float* __restrict__ sb) {
  int c = blockIdx.x * 32 + (threadIdx.x >> 3);
  int sl = threadIdx.x & 7;
  const float2* p2 = (const float2*)ps + (size_t)c * 256 + sl * 32;
  float s = 0.f, q = 0.f;
#pragma unroll 8
  for (int i = 0; i < 32; ++i) { float2 v = p2[i]; s += v.x; q += v.y; }
  s += __shfl_xor(s, 1); s += __shfl_xor(s, 2); s += __shfl_xor(s, 4);
  q += __shfl_xor(q, 1); q += __shfl_xor(q, 2); q += __shfl_xor(q, 4);
  if (sl == 0) {
    float mean = s * (1.0f / 65536.0f);
    float var = q * (1.0f / 65536.0f) - mean * mean;
    float sc = gamma[c] / sqrtf(var + 1e-5f);
    sb[c] = sc;
    sb[512 + c] = beta[c] - mean * sc;
  }
}

// ---------------- head: BN+leaky fused A-load, 256px x 64out GEMM (K=512) + decode ----------------
__global__ __launch_bounds__(256) void k_head(const unsigned short* __restrict__ cv,
                                              const unsigned short* __restrict__ w2,
                                              const float* __restrict__ bl,
                                              const float* __restrict__ bm,
                                              const float* __restrict__ sb,
                                              float* __restrict__ out) {
  __shared__ float lo[256][59];
  __shared__ float sS[512], sBb[512];
  int tid = threadIdx.x, lane = tid & 63, wv = tid >> 6;
  int pix0 = blockIdx.x * 256;
  sS[tid] = sb[tid]; sS[256 + tid] = sb[256 + tid];
  sBb[tid] = sb[512 + tid]; sBb[256 + tid] = sb[768 + tid];
  __syncthreads();

  f32x4 acc[4][4];
#pragma unroll
  for (int mf = 0; mf < 4; ++mf)
#pragma unroll
    for (int nf = 0; nf < 4; ++nf) acc[mf][nf] = (f32x4){0.f, 0.f, 0.f, 0.f};
  int ko = lane >> 4;

  for (int k0 = 0; k0 < 512; k0 += 32) {
    int c0 = k0 + ko * 8;
    f32x4 sc0 = *(const f32x4*)&sS[c0], sc1 = *(const f32x4*)&sS[c0 + 4];
    f32x4 bo0 = *(const f32x4*)&sBb[c0], bo1 = *(const f32x4*)&sBb[c0 + 4];
    bf16x8 a[4], bg[4];
#pragma unroll
    for (int f = 0; f < 4; ++f) {
      bg[f] = *(const bf16x8*)(w2 + (size_t)(f * 16 + (lane & 15)) * 512 + c0);
      u16x8 raw = *(const u16x8*)(cv + (size_t)(pix0 + wv * 64 + f * 16 + (lane & 15)) * 512 + c0);
      u16x8 av;
#pragma unroll
      for (int jj = 0; jj < 4; ++jj) {
        float v = b2f(raw[jj]) * sc0[jj] + bo0[jj];
        v = (v > 0.f) ? v : 0.1f * v;
        av[jj] = f2b(v);
      }
#pragma unroll
      for (int jj = 0; jj < 4; ++jj) {
        float v = b2f(raw[4 + jj]) * sc1[jj] + bo1[jj];
        v = (v > 0.f) ? v : 0.1f * v;
        av[4 + jj] = f2b(v);
      }
      a[f] = __builtin_bit_cast(bf16x8, av);
    }
#pragma unroll
    for (int mf = 0; mf < 4; ++mf)
#pragma unroll
      for (int nf = 0; nf < 4; ++nf)
        acc[mf][nf] = __builtin_amdgcn_mfma_f32_16x16x32_bf16(a[mf], bg[nf], acc[mf][nf], 0, 0, 0);
  }

  float bias[4]; int colv[4];
#pragma unroll
  for (int nf = 0; nf < 4; ++nf) {
    int col = nf * 16 + (lane & 15);
    colv[nf] = col;
    bias[nf] = (col < 10) ? bl[col] : ((col < 58) ? bm[col - 10] : 0.f);
  }
#pragma unroll
  for (int mf = 0; mf < 4; ++mf)
#pragma unroll
    for (int nf = 0; nf < 4; ++nf)
#pragma unroll
      for (int r = 0; r < 4; ++r) {
        int row = wv * 64 + mf * 16 + (lane >> 4) * 4 + r;
        if (colv[nf] < 58) lo[row][colv[nf]] = acc[mf][nf][r] + bias[nf];
      }
  __syncthreads();

  // ---- decode: one thread = one pixel ----
  int pix = pix0 + tid;
  int b = pix >> 12, pi = pix & 4095;
  int yi = pi >> 6, xi = pi & 63;
  float X = (float)xi, Y = (float)yi;
  const float* O = lo[tid];

  float* outP = out;
  float* outB = out + 655360;
  float* outOL = out + 1572864;
  float* outOC = out + 2752512;
  float* outML = out + 3932160;
  float* outMC = out + 4521984;
  float* outWC = out + 5111808;
  float* outOD = out + 5636096;

  float pr[10];
#pragma unroll
  for (int i = 0; i < 10; ++i) { pr[i] = O[i]; outP[(size_t)pix * 10 + i] = pr[i]; }
  const float st = 8.f, ist = 0.125f;
  float l0 = pr[0] * pr[0] * st, l1 = pr[1] * pr[1] * st;
  float l2 = pr[2] * pr[2] * st, l3 = pr[3] * pr[3] * st;
  float cx = X * st + 4.f, cy = Y * st + 4.f;
  float xmin = cx - l3, ymin = cy - l0, xmax = cx + l1, ymax = cy + l2;
  float w = l1 + l3, h = l0 + l2;
  float xc = 0.5f * (xmax + xmin), yc = 0.5f * (ymax + ymin);
  float r = sigf(pr[8]);
  float maskr = (r > 0.9f) ? 0.f : 1.f;
  float s0 = sigf(pr[4]) * maskr, s1 = sigf(pr[5]) * maskr;
  float s2 = sigf(pr[6]) * maskr, s3 = sigf(pr[7]) * maskr;
  float conf = sigf(pr[9]);
  {
    size_t bo = (size_t)pix * 14;
    outB[bo + 0] = xc; outB[bo + 1] = yc; outB[bo + 2] = w; outB[bo + 3] = h;
    outB[bo + 4] = s0; outB[bo + 5] = s1; outB[bo + 6] = s2; outB[bo + 7] = s3;
    outB[bo + 8] = r;  outB[bo + 9] = l0; outB[bo + 10] = l1; outB[bo + 11] = l2;
    outB[bo + 12] = l3; outB[bo + 13] = conf;
  }
  float x1 = xmin + s0 * w, x7 = xmax - s2 * w;
  float y5 = ymin + s1 * h, y3 = ymax - s3 * h;
  float xob = 0.5f * (x1 + x7), yob = 0.5f * (y5 + y3);
  float ov[22];
#pragma unroll
  for (int jj = 0; jj < 22; ++jj) ov[jj] = sigf(O[28 + jj]);
  float eps = ceilf(0.01f * w);
  bool c0 = x1 < xmin + eps;
  float xp0 = c0 ? x1 : xmin + ov[0] * (x1 - xmin);
  float yp0 = c0 ? ymin + ov[0] * (y3 - ymin)
                 : (y3 - ymin) / (xmin - x1 + 1e-8f) * (xp0 - x1) + ymin;
  bool c2 = x1 > xmax - eps;
  float xp2 = c2 ? x1 : xmax - ov[1] * (xmax - x1);
  float yp2 = c2 ? ymin + ov[1] * (y5 - ymin)
                 : (y5 - ymin) / (xmax - x1 + 1e-8f) * (xp2 - x1) + ymin;
  bool c6 = x7 < xmin + eps;
  float xp6 = c6 ? x7 : xmin + ov[2] * (x7 - xmin);
  float yp6 = c6 ? ymax - ov[2] * (ymax - y3)
                 : (y3 - ymax) / (xmin - x7 + 1e-8f) * (xp6 - x7) + ymax;
  bool c8c = x7 > xmax - eps;
  float xp8 = c8c ? x7 : xmax - ov[3] * (xmax - x7);
  float yp8 = c8c ? ymax - ov[3] * (ymax - y5)
                  : (y5 - ymax) / (xmax - x7 + 1e-8f) * (xp8 - x7) + ymax;

  size_t olb = ((size_t)b * 18) * 4096 + pi;
  outOL[olb + 0 * 4096] = yp0 * ist + 1.f - Y;
  outOL[olb + 1 * 4096] = xp0 * ist + 1.f - X;
  outOL[olb + 2 * 4096] = ymin * ist + 1.f - Y;
  outOL[olb + 3 * 4096] = x1 * ist - X;
  outOL[olb + 4 * 4096] = yp2 * ist + 1.f - Y;
  outOL[olb + 5 * 4096] = xp2 * ist - 1.f - X;
  outOL[olb + 6 * 4096] = y3 * ist - Y;
  outOL[olb + 7 * 4096] = xmin * ist + 1.f - X;
  outOL[olb + 8 * 4096] = 0.f;
  outOL[olb + 9 * 4096] = 0.f;
  outOL[olb + 10 * 4096] = y5 * ist - Y;
  outOL[olb + 11 * 4096] = xmax * ist - 1.f - X;
  outOL[olb + 12 * 4096] = yp6 * ist - 1.f - Y;
  outOL[olb + 13 * 4096] = xp6 * ist + 1.f - X;
  outOL[olb + 14 * 4096] = ymax * ist - 1.f - Y;
  outOL[olb + 15 * 4096] = x7 * ist - X;
  outOL[olb + 16 * 4096] = yp8 * ist - 1.f - Y;
  outOL[olb + 17 * 4096] = xp8 * ist - 1.f - X;

  float A1 = x1 - xmax, B1 = ymin - y5, A2 = xmin - x7, B2 = y3 - ymax;
  float width = 0.5f * (sqrtf(A1 * A1 + B1 * B1) + sqrtf(A2 * A2 + B2 * B2));
  float C1 = xmin - x1, D1 = y3 - ymin, C2 = x7 - xmax, D2 = ymax - y5;
  float height = 0.5f * (sqrtf(C1 * C1 + D1 * D1) + sqrtf(C2 * C2 + D2 * D2));
  float ang = 0.5f * (atanf((y5 - ymin) / (xmax - x1 + 1e-4f)) +
                      atanf((ymax - y3) / (x7 - xmin + 1e-4f)));
  float ca = cosf(ang), sa = sinf(ang);
  const float DD = 0.70710678118654752f;
  const float dyc[9] = {DD, 1.f, DD, 0.f, 0.f, 0.f, -DD, -1.f, -DD};
  const float dxc[9] = {DD, 0.f, -DD, 1.f, 0.f, -1.f, DD, 0.f, -DD};
  size_t ocb = ((size_t)b * 18) * 4096 + pi;
  size_t odb = (size_t)pix * 18;
#pragma unroll
  for (int k = 0; k < 9; ++k) {
    float xd = xob - 0.5f * width + ov[13 + k] * width;
    float yd = yob - 0.5f * height + ov[4 + k] * height;
    float ddx = xd - xob, ddy = yd - yob;
    float xd0 = ca * ddx - sa * ddy + xob;
    float xdc = fminf(fmaxf(xd0, xmin), xmax);
    float yd0 = sa * ddx + ca * ddy + yob;
    float ydc = fminf(fmaxf(yd0, ymin), ymax);
    outOC[ocb + (size_t)(2 * k) * 4096] = ydc * ist + dyc[k] - Y;
    outOC[ocb + (size_t)(2 * k + 1) * 4096] = xdc * ist + dxc[k] - X;
    outOD[odb + k] = xdc;
    outOD[odb + 9 + k] = ydc;
  }
  size_t mlb = ((size_t)b * 9) * 4096 + pi;
#pragma unroll
  for (int k = 0; k < 9; ++k) outML[mlb + (size_t)k * 4096] = sigf(O[10 + k]);
#pragma unroll
  for (int k = 0; k < 9; ++k) outMC[mlb + (size_t)k * 4096] = sigf(O[19 + k]);
  float v8[8], mx = -1e30f;
#pragma unroll
  for (int k = 0; k < 8; ++k) { v8[k] = O[50 + k]; mx = fmaxf(mx, v8[k]); }
  float sm = 0.f;
#pragma unroll
  for (int k = 0; k < 8; ++k) { v8[k] = __expf(v8[k] - mx); sm += v8[k]; }
  float inv = 1.f / sm;
  size_t wcb = ((size_t)b * 8) * 4096 + pi;
#pragma unroll
  for (int k = 0; k < 8; ++k) outWC[wcb + (size_t)k * 4096] = v8[k] * inv;
}

// ---------------- launch ----------------
extern "C" void kernel_launch(void* const* d_in, const int* in_sizes, int n_in,
                              void* d_out, int out_size, void* d_ws, size_t ws_size,
                              hipStream_t stream) {
  const float* in1 = (const float*)d_in[0];
  const float* wconv = (const float*)d_in[1];
  const float* gamma = (const float*)d_in[2];
  const float* beta = (const float*)d_in[3];
  const float* wloc = (const float*)d_in[4];
  const float* bloc = (const float*)d_in[5];
  const float* wmask = (const float*)d_in[6];
  const float* bmask = (const float*)d_in[7];
  unsigned char* ws = (unsigned char*)d_ws;
  unsigned short* xp = (unsigned short*)(ws + XP_OFF);
  unsigned short* wt = (unsigned short*)(ws + WT_OFF);
  unsigned short* w2 = (unsigned short*)(ws + W2_OFF);
  unsigned short* cv = (unsigned short*)(ws + CV_OFF);
  float* ps = (float*)(ws + PS_OFF);
  float* sb = (float*)(ws + SB_OFF);
  float* out = (float*)d_out;

  (void)hipFuncSetAttribute(reinterpret_cast<const void*>(k_conv8),
                            hipFuncAttributeMaxDynamicSharedMemorySize, 131072);

  k_prep<<<dim3(5785), dim3(256), 0, stream>>>(wconv, wloc, wmask, xp, wt, w2);
  k_pack_in<<<dim3(8192), dim3(256), 0, stream>>>(in1, xp);
  k_conv8<<<dim3(512), dim3(512), 131072, stream>>>(xp, wt, cv, ps);
  k_bnfinal<<<dim3(16), dim3(256), 0, stream>>>(ps, gamma, beta, sb);
  k_head<<<dim3(256), dim3(256), 0, stream>>>(cv, w2, bloc, bmask, sb, out);
}

// Round 4
// 211.630 us; speedup vs baseline: 1.6043x; 1.0174x over previous
//
#include <hip/hip_runtime.h>

typedef __attribute__((ext_vector_type(4))) float f32x4;
typedef __attribute__((ext_vector_type(4))) unsigned int u32x4;
typedef __attribute__((ext_vector_type(8))) unsigned short u16x8;
typedef __attribute__((ext_vector_type(8))) __bf16 bf16x8;

#define DEVFN static __device__ __forceinline__

DEVFN unsigned short f2b(float f) {
  unsigned u = __builtin_bit_cast(unsigned, f);
  u += 0x7fffu + ((u >> 16) & 1u);
  return (unsigned short)(u >> 16);
}
DEVFN float b2f(unsigned short h) {
  unsigned u = ((unsigned)h) << 16;
  return __builtin_bit_cast(float, u);
}
DEVFN float sigf(float x) { return 1.0f / (1.0f + __expf(-x)); }

// ---------------- geometry ----------------
#define CS 264
#define KPAD 2432
#define NTILE 38

// ---------------- workspace layout (bytes) ----------------
#define XP_BYTES (16ull*66*66*CS*2)
#define WT_BYTES (512ull*KPAD*2)
#define W2_BYTES (64ull*512*2)
#define CV_BYTES (65536ull*512*2)
#define PS_BYTES (512ull*256*2*4)
#define XP_OFF 0ull
#define WT_OFF (XP_OFF + XP_BYTES)
#define W2_OFF (WT_OFF + WT_BYTES)
#define CV_OFF (W2_OFF + W2_BYTES)
#define PS_OFF (CV_OFF + CV_BYTES)
#define SB_OFF (PS_OFF + PS_BYTES)

#define GLOAD16(gp, lp) __builtin_amdgcn_global_load_lds( \
    (__attribute__((address_space(1))) void*)(gp),        \
    (__attribute__((address_space(3))) void*)(lp), 16, 0, 0)

#define BAR()  do { __builtin_amdgcn_s_barrier(); __builtin_amdgcn_sched_barrier(0); } while (0)
#define WLG0() do { asm volatile("s_waitcnt lgkmcnt(0)" ::: "memory"); __builtin_amdgcn_sched_barrier(0); } while (0)

// ---------------- merged prep kernel ----------------
__global__ void k_prep(const float* __restrict__ wc, const float* __restrict__ wl,
                       const float* __restrict__ wm, unsigned short* __restrict__ xp,
                       unsigned short* __restrict__ wt, unsigned short* __restrict__ w2) {
  int bid = blockIdx.x, tid = threadIdx.x;
  if (bid < 537) {
    int idx = bid * 256 + tid;
    if (idx >= 137280) return;
    int cell_i = idx / 33, u = idx - cell_i * 33;
    int b = cell_i / 260, r = cell_i - b * 260;
    int y, x;
    if (r < 66) { y = 0; x = r; }
    else if (r < 132) { y = 65; x = r - 66; }
    else if (r < 196) { y = r - 131; x = 0; }
    else { y = r - 195; x = 65; }
    int cell = (b * 66 + y) * 66 + x;
    *(u32x4*)((unsigned char*)xp + (size_t)cell * (CS * 2) + u * 16) = (u32x4){0u, 0u, 0u, 0u};
  } else if (bid < 793) {
    int pid = (bid - 537) * 256 + tid;
    int b = pid >> 12, pi = pid & 4095, y = pi >> 6, x = pi & 63;
    u16x8 v0 = (u16x8){0, 0, 0, 0, 0, 0, 0, 0};
    v0[0] = f2b((float)x); v0[1] = f2b((float)y);
    *(u16x8*)(xp + ((size_t)((b * 66 + y + 1) * 66 + x + 1)) * CS + 256) = v0;
  } else if (bid < 5657) {
    int idx = (bid - 793) * 256 + tid;
    int o = idx / KPAD, k = idx - o * KPAD;
    int dy = k / 800, t = k - dy * 800;
    int dx = t / CS, ci = t - dx * CS;
    float v = (dy < 3 && dx < 3 && ci < 258) ? wc[(size_t)(o * 258 + ci) * 9 + dy * 3 + dx] : 0.f;
    wt[idx] = f2b(v);
  } else {
    int idx = (bid - 5657) * 256 + tid;
    int o = idx >> 9, k = idx & 511;
    float v = 0.f;
    if (o < 10) v = wl[o * 512 + k];
    else if (o < 58) v = wm[(o - 10) * 512 + k];
    w2[idx] = f2b(v);
  }
}

// input1 (16,256,64,64) f32 -> Xp[b][y+1][x+1][c] bf16 (c<256)
__global__ void k_pack_in(const float* __restrict__ in1, unsigned short* __restrict__ xp) {
  __shared__ float lt[32][65];
  int tid = threadIdx.x;
  int bid = blockIdx.x;
  int cg = bid & 7, y = (bid >> 3) & 63, b = bid >> 9;
  int x = tid & 63, cr = tid >> 6;
#pragma unroll
  for (int i = 0; i < 8; ++i) {
    int cl = i * 4 + cr;
    lt[cl][x] = in1[(((size_t)(b * 256 + cg * 32 + cl) * 64 + y) * 64) + x];
  }
  __syncthreads();
  int xx = tid >> 2, ch = tid & 3;
  u16x8 v;
#pragma unroll
  for (int j = 0; j < 8; ++j) v[j] = f2b(lt[ch * 8 + j][xx]);
  size_t base = ((size_t)((b * 66 + y + 1) * 66 + xx + 1)) * CS + cg * 32 + ch * 8;
  *(u16x8*)(xp + base) = v;
}

// ---------------- conv: 256x256 tile, BK=64, 4 phases x 38 K-tiles ----------------
// Phase p: {[ph0: 8 start-reads]; lgkmcnt(0); 16 MFMA interleaved with next-phase ds_reads;
//           stage gloads; [ph3: counted vmcnt]; s_barrier}. 4 barriers per K-tile.
// K-split: ph0=m-lo*k0, ph1=m-lo*k1, ph2=m-hi*k0, ph3=m-hi*k1 (af regs reused lo->hi).
__global__ __launch_bounds__(512, 2) void k_conv8(const unsigned short* __restrict__ xp,
                                                  const unsigned short* __restrict__ wt,
                                                  unsigned short* __restrict__ cv,
                                                  float* __restrict__ ps) {
  extern __shared__ char smem[];
  int tid = threadIdx.x, lane = tid & 63, wv = tid >> 6;
  int wm = wv >> 2, wn = wv & 3;
  int bid = blockIdx.x;
  int xcd = bid & 7, j = bid >> 3;
  int nt = j & 1;
  int mt = xcd * 32 + (j >> 1);
  int n0 = nt * 256;
  int pix0 = mt * 256;
  int b = pix0 >> 12, pi0 = pix0 & 4095;

  // ---- staging constants ----
  int srow = tid >> 3;
  int ug = (tid & 7) ^ (srow & 7);
  unsigned cellB[4], oB[4];
#pragma unroll
  for (int jj = 0; jj < 4; ++jj) {
    int pi = pi0 + srow + 64 * jj;
    int yy = pi >> 6, xx = pi & 63;
    cellB[jj] = (unsigned)((b * 66 + yy) * 66 + xx) * (CS * 2);
    oB[jj] = (unsigned)(n0 + srow + 64 * jj) * (KPAD * 2);
  }

  auto stageA = [&](int tau, int h) {
    int buf = tau & 1;
    unsigned k = (unsigned)tau * 64u + (unsigned)ug * 8u;
    unsigned dy = k / 800u;
    unsigned t = k - dy * 800u;
    unsigned off = dy * (66u * CS * 2u) + t * 2u;
    const unsigned char* g = (const unsigned char*)xp;
    char* l = smem + buf * 65536 + h * 16384;
    GLOAD16(g + cellB[h * 2] + off, l + tid * 16);
    GLOAD16(g + cellB[h * 2 + 1] + off, l + 8192 + tid * 16);
  };
  auto stageB = [&](int tau, int h) {
    int buf = tau & 1;
    unsigned k2 = ((unsigned)tau * 64u + (unsigned)ug * 8u) * 2u;
    const unsigned char* g = (const unsigned char*)wt;
    char* l = smem + buf * 65536 + 32768 + h * 16384;
    GLOAD16(g + oB[h * 2] + k2, l + tid * 16);
    GLOAD16(g + oB[h * 2 + 1] + k2, l + 8192 + tid * 16);
  };

  // ---- fragment read constants ----
  unsigned aoffb[8], boffb[4];
#pragma unroll
  for (int mf = 0; mf < 8; ++mf) aoffb[mf] = (unsigned)(wm * 128 + mf * 16 + (lane & 15)) * 128u;
#pragma unroll
  for (int nf = 0; nf < 4; ++nf) boffb[nf] = 32768u + (unsigned)(wn * 64 + nf * 16 + (lane & 15)) * 128u;
  int ko = (lane >> 4) & 3, xm = lane & 7;
  unsigned un[2];
#pragma unroll
  for (int kk = 0; kk < 2; ++kk) un[kk] = (unsigned)(((kk * 4 + ko) ^ xm) * 16);

  f32x4 acc[8][4];
#pragma unroll
  for (int i = 0; i < 8; ++i)
#pragma unroll
    for (int jj = 0; jj < 4; ++jj) acc[i][jj] = (f32x4){0.f, 0.f, 0.f, 0.f};

  // ---- prologue: tile0 fully + tile1 B halves ----
  stageB(0, 0); stageB(0, 1); stageA(0, 0); stageA(0, 1); stageB(1, 0); stageB(1, 1);
  asm volatile("s_waitcnt vmcnt(4)" ::: "memory");
  __builtin_amdgcn_sched_barrier(0);
  BAR();

  bf16x8 af[4][2], bfr[4][2];
#define MM(mi, ni, kk, ab) acc[(ab) + (mi)][(ni)] = \
    __builtin_amdgcn_mfma_f32_16x16x32_bf16(af[(mi)][(kk)], bfr[(ni)][(kk)], acc[(ab) + (mi)][(ni)], 0, 0, 0)

#pragma unroll 1
  for (int tau = 0; tau < NTILE; ++tau) {
    bool sA = tau < NTILE - 1, sB = tau < NTILE - 2;
    const char* base = smem + (tau & 1) * 65536;
    auto rdA = [&](int s, int kk, int hi) { af[s][kk] = *(const bf16x8*)(base + aoffb[hi * 4 + s] + un[kk]); };
    auto rdB = [&](int s, int kk) { bfr[s][kk] = *(const bf16x8*)(base + boffb[s] + un[kk]); };

    // ---- ph0: m-lo x k0; tail prefetch: af-lo-k1 + bf-k1 (8 reads)
    rdA(0, 0, 0); rdA(1, 0, 0); rdA(2, 0, 0); rdA(3, 0, 0);
    rdB(0, 0); rdB(1, 0); rdB(2, 0); rdB(3, 0);
    WLG0();
    __builtin_amdgcn_s_setprio(1);
    MM(0, 0, 0, 0); MM(0, 1, 0, 0); rdA(0, 1, 0);
    MM(0, 2, 0, 0); MM(0, 3, 0, 0); rdA(1, 1, 0);
    MM(1, 0, 0, 0); MM(1, 1, 0, 0); rdA(2, 1, 0);
    MM(1, 2, 0, 0); MM(1, 3, 0, 0); rdA(3, 1, 0);
    MM(2, 0, 0, 0); MM(2, 1, 0, 0); rdB(0, 1);
    MM(2, 2, 0, 0); MM(2, 3, 0, 0); rdB(1, 1);
    MM(3, 0, 0, 0); MM(3, 1, 0, 0); rdB(2, 1);
    MM(3, 2, 0, 0); MM(3, 3, 0, 0); rdB(3, 1);
    __builtin_amdgcn_s_setprio(0);
    if (sA) stageA(tau + 1, 0);
    BAR();

    // ---- ph1: m-lo x k1; tail: af-hi-k0 (4 reads)
    WLG0();
    __builtin_amdgcn_s_setprio(1);
    MM(0, 0, 1, 0); MM(0, 1, 1, 0); MM(0, 2, 1, 0); MM(0, 3, 1, 0); rdA(0, 0, 1);
    MM(1, 0, 1, 0); MM(1, 1, 1, 0); MM(1, 2, 1, 0); MM(1, 3, 1, 0); rdA(1, 0, 1);
    MM(2, 0, 1, 0); MM(2, 1, 1, 0); MM(2, 2, 1, 0); MM(2, 3, 1, 0); rdA(2, 0, 1);
    MM(3, 0, 1, 0); MM(3, 1, 1, 0); MM(3, 2, 1, 0); MM(3, 3, 1, 0); rdA(3, 0, 1);
    __builtin_amdgcn_s_setprio(0);
    if (sA) stageA(tau + 1, 1);
    BAR();

    // ---- ph2: m-hi x k0; tail: af-hi-k1 (4 reads)
    WLG0();
    __builtin_amdgcn_s_setprio(1);
    MM(0, 0, 0, 4); MM(0, 1, 0, 4); MM(0, 2, 0, 4); MM(0, 3, 0, 4); rdA(0, 1, 1);
    MM(1, 0, 0, 4); MM(1, 1, 0, 4); MM(1, 2, 0, 4); MM(1, 3, 0, 4); rdA(1, 1, 1);
    MM(2, 0, 0, 4); MM(2, 1, 0, 4); MM(2, 2, 0, 4); MM(2, 3, 0, 4); rdA(2, 1, 1);
    MM(3, 0, 0, 4); MM(3, 1, 0, 4); MM(3, 2, 0, 4); MM(3, 3, 0, 4); rdA(3, 1, 1);
    __builtin_amdgcn_s_setprio(0);
    if (sB) stageB(tau + 2, 0);
    BAR();

    // ---- ph3: m-hi x k1; no tail; counted vmcnt
    WLG0();
    __builtin_amdgcn_s_setprio(1);
    MM(0, 0, 1, 4); MM(0, 1, 1, 4); MM(0, 2, 1, 4); MM(0, 3, 1, 4);
    MM(1, 0, 1, 4); MM(1, 1, 1, 4); MM(1, 2, 1, 4); MM(1, 3, 1, 4);
    MM(2, 0, 1, 4); MM(2, 1, 1, 4); MM(2, 2, 1, 4); MM(2, 3, 1, 4);
    MM(3, 0, 1, 4); MM(3, 1, 1, 4); MM(3, 2, 1, 4); MM(3, 3, 1, 4);
    __builtin_amdgcn_s_setprio(0);
    if (sB) stageB(tau + 2, 1);
    if (tau < NTILE - 2) { asm volatile("s_waitcnt vmcnt(4)" ::: "memory"); __builtin_amdgcn_sched_barrier(0); }
    else if (tau == NTILE - 2) { asm volatile("s_waitcnt vmcnt(0)" ::: "memory"); __builtin_amdgcn_sched_barrier(0); }
    BAR();
  }
#undef MM

  // ---- epilogue 1: raw conv -> cv (bf16), via LDS repack (XOR-4 store swizzle) ----
  unsigned short* l16 = (unsigned short*)smem;
#pragma unroll
  for (int mf = 0; mf < 8; ++mf)
#pragma unroll
    for (int nf = 0; nf < 4; ++nf)
#pragma unroll
      for (int r = 0; r < 4; ++r) {
        int row = wm * 128 + mf * 16 + (lane >> 4) * 4 + r;
        int col = wn * 64 + nf * 16 + (lane & 15);
        int colx = col ^ (((row >> 2) & 3) << 3);
        l16[row * 256 + colx] = f2b(acc[mf][nf][r]);
      }
  __syncthreads();
#pragma unroll
  for (int i = 0; i < 16; ++i) {
    int q = tid + 512 * i;
    int prow = q >> 5, c16 = q & 31;
    int c16g = c16 ^ ((prow >> 2) & 3);
    *(u16x8*)(cv + ((size_t)(pix0 + prow) * 512 + n0 + c16g * 8)) = *(const u16x8*)(l16 + q * 8);
  }
  __syncthreads();

  // ---- epilogue 2: BN partial stats from f32 acc ----
  float* lf = (float*)smem;
  float sv[4], qv[4];
#pragma unroll
  for (int nf = 0; nf < 4; ++nf) {
    float s = 0.f, q = 0.f;
#pragma unroll
    for (int mf = 0; mf < 8; ++mf)
#pragma unroll
      for (int r = 0; r < 4; ++r) { float v = acc[mf][nf][r]; s += v; q += v * v; }
    s += __shfl_xor(s, 16); s += __shfl_xor(s, 32);
    q += __shfl_xor(q, 16); q += __shfl_xor(q, 32);
    sv[nf] = s; qv[nf] = q;
  }
  if (lane < 16) {
#pragma unroll
    for (int nf = 0; nf < 4; ++nf) {
      int ch = wn * 64 + nf * 16 + lane;
      lf[wm * 256 + ch] = sv[nf];
      lf[512 + wm * 256 + ch] = qv[nf];
    }
  }
  __syncthreads();
  if (tid < 256) {
    float S = lf[tid] + lf[256 + tid];
    float Q = lf[512 + tid] + lf[768 + tid];
    ((float2*)ps)[(size_t)(n0 + tid) * 256 + mt] = make_float2(S, Q);
  }
}

// ---------------- BN finalize: scale/bias (16 blocks, shfl-reduced) ----------------
__global__ void k_bnfinal(const float* __restrict__ ps, const float* __restrict__ gamma,
                          const float* __restrict__ beta, float* __restrict__ sb) {
  int c = blockIdx.x * 32 + (threadIdx.x >> 3);
  int sl = threadIdx.x & 7;
  const float2* p2 = (const float2*)ps + (size_t)c * 256 + sl * 32;
  float s = 0.f, q = 0.f;
#pragma unroll 8
  for (int i = 0; i < 32; ++i) { float2 v = p2[i]; s += v.x; q += v.y; }
  s += __shfl_xor(s, 1); s += __shfl_xor(s, 2); s += __shfl_xor(s, 4);
  q += __shfl_xor(q, 1); q += __shfl_xor(q, 2); q += __shfl_xor(q, 4);
  if (sl == 0) {
    float mean = s * (1.0f / 65536.0f);
    float var = q * (1.0f / 65536.0f) - mean * mean;
    float sc = gamma[c] / sqrtf(var + 1e-5f);
    sb[c] = sc;
    sb[512 + c] = beta[c] - mean * sc;
  }
}

// ---------------- head: BN+leaky fused A-load, 256px x 64out GEMM (K=512) + decode ----------------
__global__ __launch_bounds__(256) void k_head(const unsigned short* __restrict__ cv,
                                              const unsigned short* __restrict__ w2,
                                              const float* __restrict__ bl,
                                              const float* __restrict__ bm,
                                              const float* __restrict__ sb,
                                              float* __restrict__ out) {
  __shared__ float lo[256][59];
  __shared__ float sS[512], sBb[512];
  int tid = threadIdx.x, lane = tid & 63, wv = tid >> 6;
  int pix0 = blockIdx.x * 256;
  sS[tid] = sb[tid]; sS[256 + tid] = sb[256 + tid];
  sBb[tid] = sb[512 + tid]; sBb[256 + tid] = sb[768 + tid];
  __syncthreads();

  f32x4 acc[4][4];
#pragma unroll
  for (int mf = 0; mf < 4; ++mf)
#pragma unroll
    for (int nf = 0; nf < 4; ++nf) acc[mf][nf] = (f32x4){0.f, 0.f, 0.f, 0.f};
  int ko = lane >> 4;

  for (int k0 = 0; k0 < 512; k0 += 32) {
    int c0 = k0 + ko * 8;
    f32x4 sc0 = *(const f32x4*)&sS[c0], sc1 = *(const f32x4*)&sS[c0 + 4];
    f32x4 bo0 = *(const f32x4*)&sBb[c0], bo1 = *(const f32x4*)&sBb[c0 + 4];
    bf16x8 a[4], bg[4];
#pragma unroll
    for (int f = 0; f < 4; ++f) {
      bg[f] = *(const bf16x8*)(w2 + (size_t)(f * 16 + (lane & 15)) * 512 + c0);
      u16x8 raw = *(const u16x8*)(cv + (size_t)(pix0 + wv * 64 + f * 16 + (lane & 15)) * 512 + c0);
      u16x8 av;
#pragma unroll
      for (int jj = 0; jj < 4; ++jj) {
        float v = b2f(raw[jj]) * sc0[jj] + bo0[jj];
        v = (v > 0.f) ? v : 0.1f * v;
        av[jj] = f2b(v);
      }
#pragma unroll
      for (int jj = 0; jj < 4; ++jj) {
        float v = b2f(raw[4 + jj]) * sc1[jj] + bo1[jj];
        v = (v > 0.f) ? v : 0.1f * v;
        av[4 + jj] = f2b(v);
      }
      a[f] = __builtin_bit_cast(bf16x8, av);
    }
#pragma unroll
    for (int mf = 0; mf < 4; ++mf)
#pragma unroll
      for (int nf = 0; nf < 4; ++nf)
        acc[mf][nf] = __builtin_amdgcn_mfma_f32_16x16x32_bf16(a[mf], bg[nf], acc[mf][nf], 0, 0, 0);
  }

  float bias[4]; int colv[4];
#pragma unroll
  for (int nf = 0; nf < 4; ++nf) {
    int col = nf * 16 + (lane & 15);
    colv[nf] = col;
    bias[nf] = (col < 10) ? bl[col] : ((col < 58) ? bm[col - 10] : 0.f);
  }
#pragma unroll
  for (int mf = 0; mf < 4; ++mf)
#pragma unroll
    for (int nf = 0; nf < 4; ++nf)
#pragma unroll
      for (int r = 0; r < 4; ++r) {
        int row = wv * 64 + mf * 16 + (lane >> 4) * 4 + r;
        if (colv[nf] < 58) lo[row][colv[nf]] = acc[mf][nf][r] + bias[nf];
      }
  __syncthreads();

  // ---- decode: one thread = one pixel ----
  int pix = pix0 + tid;
  int b = pix >> 12, pi = pix & 4095;
  int yi = pi >> 6, xi = pi & 63;
  float X = (float)xi, Y = (float)yi;
  const float* O = lo[tid];

  float* outP = out;
  float* outB = out + 655360;
  float* outOL = out + 1572864;
  float* outOC = out + 2752512;
  float* outML = out + 3932160;
  float* outMC = out + 4521984;
  float* outWC = out + 5111808;
  float* outOD = out + 5636096;

  float pr[10];
#pragma unroll
  for (int i = 0; i < 10; ++i) { pr[i] = O[i]; outP[(size_t)pix * 10 + i] = pr[i]; }
  const float st = 8.f, ist = 0.125f;
  float l0 = pr[0] * pr[0] * st, l1 = pr[1] * pr[1] * st;
  float l2 = pr[2] * pr[2] * st, l3 = pr[3] * pr[3] * st;
  float cx = X * st + 4.f, cy = Y * st + 4.f;
  float xmin = cx - l3, ymin = cy - l0, xmax = cx + l1, ymax = cy + l2;
  float w = l1 + l3, h = l0 + l2;
  float xc = 0.5f * (xmax + xmin), yc = 0.5f * (ymax + ymin);
  float r = sigf(pr[8]);
  float maskr = (r > 0.9f) ? 0.f : 1.f;
  float s0 = sigf(pr[4]) * maskr, s1 = sigf(pr[5]) * maskr;
  float s2 = sigf(pr[6]) * maskr, s3 = sigf(pr[7]) * maskr;
  float conf = sigf(pr[9]);
  {
    size_t bo = (size_t)pix * 14;
    outB[bo + 0] = xc; outB[bo + 1] = yc; outB[bo + 2] = w; outB[bo + 3] = h;
    outB[bo + 4] = s0; outB[bo + 5] = s1; outB[bo + 6] = s2; outB[bo + 7] = s3;
    outB[bo + 8] = r;  outB[bo + 9] = l0; outB[bo + 10] = l1; outB[bo + 11] = l2;
    outB[bo + 12] = l3; outB[bo + 13] = conf;
  }
  float x1 = xmin + s0 * w, x7 = xmax - s2 * w;
  float y5 = ymin + s1 * h, y3 = ymax - s3 * h;
  float xob = 0.5f * (x1 + x7), yob = 0.5f * (y5 + y3);
  float ov[22];
#pragma unroll
  for (int jj = 0; jj < 22; ++jj) ov[jj] = sigf(O[28 + jj]);
  float eps = ceilf(0.01f * w);
  bool c0 = x1 < xmin + eps;
  float xp0 = c0 ? x1 : xmin + ov[0] * (x1 - xmin);
  float yp0 = c0 ? ymin + ov[0] * (y3 - ymin)
                 : (y3 - ymin) / (xmin - x1 + 1e-8f) * (xp0 - x1) + ymin;
  bool c2 = x1 > xmax - eps;
  float xp2 = c2 ? x1 : xmax - ov[1] * (xmax - x1);
  float yp2 = c2 ? ymin + ov[1] * (y5 - ymin)
                 : (y5 - ymin) / (xmax - x1 + 1e-8f) * (xp2 - x1) + ymin;
  bool c6 = x7 < xmin + eps;
  float xp6 = c6 ? x7 : xmin + ov[2] * (x7 - xmin);
  float yp6 = c6 ? ymax - ov[2] * (ymax - y3)
                 : (y3 - ymax) / (xmin - x7 + 1e-8f) * (xp6 - x7) + ymax;
  bool c8c = x7 > xmax - eps;
  float xp8 = c8c ? x7 : xmax - ov[3] * (xmax - x7);
  float yp8 = c8c ? ymax - ov[3] * (ymax - y5)
                  : (y5 - ymax) / (xmax - x7 + 1e-8f) * (xp8 - x7) + ymax;

  size_t olb = ((size_t)b * 18) * 4096 + pi;
  outOL[olb + 0 * 4096] = yp0 * ist + 1.f - Y;
  outOL[olb + 1 * 4096] = xp0 * ist + 1.f - X;
  outOL[olb + 2 * 4096] = ymin * ist + 1.f - Y;
  outOL[olb + 3 * 4096] = x1 * ist - X;
  outOL[olb + 4 * 4096] = yp2 * ist + 1.f - Y;
  outOL[olb + 5 * 4096] = xp2 * ist - 1.f - X;
  outOL[olb + 6 * 4096] = y3 * ist - Y;
  outOL[olb + 7 * 4096] = xmin * ist + 1.f - X;
  outOL[olb + 8 * 4096] = 0.f;
  outOL[olb + 9 * 4096] = 0.f;
  outOL[olb + 10 * 4096] = y5 * ist - Y;
  outOL[olb + 11 * 4096] = xmax * ist - 1.f - X;
  outOL[olb + 12 * 4096] = yp6 * ist - 1.f - Y;
  outOL[olb + 13 * 4096] = xp6 * ist + 1.f - X;
  outOL[olb + 14 * 4096] = ymax * ist - 1.f - Y;
  outOL[olb + 15 * 4096] = x7 * ist - X;
  outOL[olb + 16 * 4096] = yp8 * ist - 1.f - Y;
  outOL[olb + 17 * 4096] = xp8 * ist - 1.f - X;

  float A1 = x1 - xmax, B1 = ymin - y5, A2 = xmin - x7, B2 = y3 - ymax;
  float width = 0.5f * (sqrtf(A1 * A1 + B1 * B1) + sqrtf(A2 * A2 + B2 * B2));
  float C1 = xmin - x1, D1 = y3 - ymin, C2 = x7 - xmax, D2 = ymax - y5;
  float height = 0.5f * (sqrtf(C1 * C1 + D1 * D1) + sqrtf(C2 * C2 + D2 * D2));
  float ang = 0.5f * (atanf((y5 - ymin) / (xmax - x1 + 1e-4f)) +
                      atanf((ymax - y3) / (x7 - xmin + 1e-4f)));
  float ca = cosf(ang), sa = sinf(ang);
  const float DD = 0.70710678118654752f;
  const float dyc[9] = {DD, 1.f, DD, 0.f, 0.f, 0.f, -DD, -1.f, -DD};
  const float dxc[9] = {DD, 0.f, -DD, 1.f, 0.f, -1.f, DD, 0.f, -DD};
  size_t ocb = ((size_t)b * 18) * 4096 + pi;
  size_t odb = (size_t)pix * 18;
#pragma unroll
  for (int k = 0; k < 9; ++k) {
    float xd = xob - 0.5f * width + ov[13 + k] * width;
    float yd = yob - 0.5f * height + ov[4 + k] * height;
    float ddx = xd - xob, ddy = yd - yob;
    float xd0 = ca * ddx - sa * ddy + xob;
    float xdc = fminf(fmaxf(xd0, xmin), xmax);
    float yd0 = sa * ddx + ca * ddy + yob;
    float ydc = fminf(fmaxf(yd0, ymin), ymax);
    outOC[ocb + (size_t)(2 * k) * 4096] = ydc * ist + dyc[k] - Y;
    outOC[ocb + (size_t)(2 * k + 1) * 4096] = xdc * ist + dxc[k] - X;
    outOD[odb + k] = xdc;
    outOD[odb + 9 + k] = ydc;
  }
  size_t mlb = ((size_t)b * 9) * 4096 + pi;
#pragma unroll
  for (int k = 0; k < 9; ++k) outML[mlb + (size_t)k * 4096] = sigf(O[10 + k]);
#pragma unroll
  for (int k = 0; k < 9; ++k) outMC[mlb + (size_t)k * 4096] = sigf(O[19 + k]);
  float v8[8], mx = -1e30f;
#pragma unroll
  for (int k = 0; k < 8; ++k) { v8[k] = O[50 + k]; mx = fmaxf(mx, v8[k]); }
  float sm = 0.f;
#pragma unroll
  for (int k = 0; k < 8; ++k) { v8[k] = __expf(v8[k] - mx); sm += v8[k]; }
  float inv = 1.f / sm;
  size_t wcb = ((size_t)b * 8) * 4096 + pi;
#pragma unroll
  for (int k = 0; k < 8; ++k) outWC[wcb + (size_t)k * 4096] = v8[k] * inv;
}

// ---------------- launch ----------------
extern "C" void kernel_launch(void* const* d_in, const int* in_sizes, int n_in,
                              void* d_out, int out_size, void* d_ws, size_t ws_size,
                              hipStream_t stream) {
  const float* in1 = (const float*)d_in[0];
  const float* wconv = (const float*)d_in[1];
  const float* gamma = (const float*)d_in[2];
  const float* beta = (const float*)d_in[3];
  const float* wloc = (const float*)d_in[4];
  const float* bloc = (const float*)d_in[5];
  const float* wmask = (const float*)d_in[6];
  const float* bmask = (const float*)d_in[7];
  unsigned char* ws = (unsigned char*)d_ws;
  unsigned short* xp = (unsigned short*)(ws + XP_OFF);
  unsigned short* wt = (unsigned short*)(ws + WT_OFF);
  unsigned short* w2 = (unsigned short*)(ws + W2_OFF);
  unsigned short* cv = (unsigned short*)(ws + CV_OFF);
  float* ps = (float*)(ws + PS_OFF);
  float* sb = (float*)(ws + SB_OFF);
  float* out = (float*)d_out;

  (void)hipFuncSetAttribute(reinterpret_cast<const void*>(k_conv8),
                            hipFuncAttributeMaxDynamicSharedMemorySize, 131072);

  k_prep<<<dim3(5785), dim3(256), 0, stream>>>(wconv, wloc, wmask, xp, wt, w2);
  k_pack_in<<<dim3(8192), dim3(256), 0, stream>>>(in1, xp);
  k_conv8<<<dim3(512), dim3(512), 131072, stream>>>(xp, wt, cv, ps);
  k_bnfinal<<<dim3(16), dim3(256), 0, stream>>>(ps, gamma, beta, sb);
  k_head<<<dim3(256), dim3(256), 0, stream>>>(cv, w2, bloc, bmask, sb, out);
}